// Round 8
// baseline (550.058 us; speedup 1.0000x reference)
//
#include <hip/hip_runtime.h>
#include <stdint.h>

#define N_NODES 10000
#define N_EDGES 160000
#define E_TOT   170000   // edges + self loops
#define IN_CH   1030
#define HC      1024
#define OUT_CH  49
#define NEG_SLOPE 0.2f
#define LN_EPS 1e-5f

#define MPAD  10112   // 79 * 128
#define K1PAD 1088    // 17 * 64 (1030 padded to BK=64 multiple)

typedef __attribute__((ext_vector_type(8))) __bf16 bf16x8;
typedef __attribute__((ext_vector_type(4))) float floatx4;
typedef __attribute__((ext_vector_type(2))) float floatx2;

static __device__ __forceinline__ unsigned short f2bf(float f) {
  union { float f; uint32_t u; } v; v.f = f;
  uint32_t u = v.u;
  u += 0x7fffu + ((u >> 16) & 1u);   // round-to-nearest-even
  return (unsigned short)(u >> 16);
}
// unpack 2 bf16 (packed in a dword) -> 2 fp32
static __device__ __forceinline__ floatx2 unpk2(uint32_t u) {
  union { uint32_t i; float f; } a, b;
  a.i = u << 16; b.i = u & 0xffff0000u;
  floatx2 r; r.x = a.f; r.y = b.f; return r;
}
static __device__ __forceinline__ floatx2 max2(floatx2 a, floatx2 b) {
  floatx2 r; r.x = fmaxf(a.x, b.x); r.y = fmaxf(a.y, b.y); return r;
}
static __device__ __forceinline__ uint32_t pk2bf(float a, float b) {
  return (uint32_t)f2bf(a) | ((uint32_t)f2bf(b) << 16);
}

// ---------------- casts / transposes ----------------

__global__ void cast_x_kernel(const float* __restrict__ x, unsigned short* __restrict__ xa,
                              int* __restrict__ counts, int* __restrict__ cursor) {
  int idx = blockIdx.x * 256 + threadIdx.x;       // over N_NODES * K1PAD
  if (idx < N_NODES) { counts[idx] = 0; cursor[idx] = 0; }  // replaces 2 memsets
  if (idx >= N_NODES * K1PAD) return;
  int m = idx / K1PAD, k = idx - m * K1PAD;
  float v = (k < IN_CH) ? x[m * IN_CH + k] : 0.f;
  xa[idx] = f2bf(v);
}

// out[n*Kout + k] = (k < Kvalid ? W[k][n] : 0); W col picked from wa/wb by split
__global__ void transpose_cast_kernel(const float* __restrict__ wa, const float* __restrict__ wb,
                                      int split, int lda, int ldb,
                                      int Kvalid, int Kout, unsigned short* __restrict__ out) {
  __shared__ float tile[32][33];
  int n0 = blockIdx.x * 32, k0 = blockIdx.y * 32;
  int tx = threadIdx.x, ty = threadIdx.y;  // 32 x 8
#pragma unroll
  for (int i = 0; i < 4; i++) {
    int k = k0 + ty + i * 8;
    int n = n0 + tx;
    float v = 0.f;
    if (k < Kvalid) v = (n < split) ? wa[(size_t)k * lda + n] : wb[(size_t)k * ldb + (n - split)];
    tile[ty + i * 8][tx] = v;
  }
  __syncthreads();
#pragma unroll
  for (int i = 0; i < 4; i++) {
    int n = n0 + ty + i * 8;
    int k = k0 + tx;
    out[(size_t)n * Kout + k] = f2bf(tile[tx][ty + i * 8]);
  }
}

__global__ void w2t_kernel(const float* __restrict__ w2, float* __restrict__ out) {
  int o = blockIdx.x;            // 49 blocks
  int k = threadIdx.x;           // 256 threads
  out[o * 256 + k] = w2[k * OUT_CH + o];
}

// ---------------- CSR build (group edges by dst; store SRC ids directly) ----------------

__global__ void count_kernel(const int* __restrict__ dstArr, int* __restrict__ counts) {
  int e = blockIdx.x * 256 + threadIdx.x;
  if (e >= E_TOT) return;
  int d = (e < N_EDGES) ? dstArr[e] : (e - N_EDGES);
  atomicAdd(&counts[d], 1);
}

// two-level exclusive scan, 256 threads, 40 elems/thread serial
__global__ __launch_bounds__(256) void scan_kernel(const int* __restrict__ counts,
                                                   int* __restrict__ rstart) {
  __shared__ int sm[256];
  int t = threadIdx.x;
  int b0 = t * 40;
  int b1 = b0 + 40; if (b1 > N_NODES) b1 = N_NODES; if (b0 > N_NODES) b0 = N_NODES;
  int s = 0;
  for (int i = b0; i < b1; i++) s += counts[i];
  sm[t] = s; __syncthreads();
  for (int st = 1; st < 256; st <<= 1) {
    int add = (t >= st) ? sm[t - st] : 0;
    __syncthreads();
    sm[t] += add;
    __syncthreads();
  }
  int run = sm[t] - s;   // exclusive prefix of this thread's chunk
  for (int i = b0; i < b1; i++) { rstart[i] = run; run += counts[i]; }
  if (t == 255) rstart[N_NODES] = run;
}

__global__ void scatter_kernel(const int* __restrict__ srcArr, const int* __restrict__ dstArr,
                               const int* __restrict__ row_start,
                               int* __restrict__ cursor, int* __restrict__ csrsrc) {
  int e = blockIdx.x * 256 + threadIdx.x;
  if (e >= E_TOT) return;
  int d, sv;
  if (e < N_EDGES) { d = dstArr[e]; sv = srcArr[e]; }
  else { d = e - N_EDGES; sv = d; }     // self loop: src == dst
  int pos = atomicAdd(&cursor[d], 1);
  csrsrc[row_start[d] + pos] = sv;
}

// ---------------- bf16 MFMA GEMM: 128x128 tile, BK=64, XOR-swizzled LDS ----------------
// (R5/R7 single-buffer structure; dbuf regressed — see R6.)
// A: [M][K] bf16 (rows padded), Bt: [N][K] bf16. K must be a multiple of 64.
// LDS layout: slab of 128 rows x 64 cols; 16B chunk j of row r stored at slot (j ^ (r&7)).
// MODE 0: Cf = v+bias; MODE 1: ELU -> Cf; MODE 2: all-bf16 -> Cb[m*2048+n].
template <int MODE>
__global__ __launch_bounds__(256) void gemm_bf16(
    const unsigned short* __restrict__ A, const unsigned short* __restrict__ Bt,
    float* __restrict__ Cf, unsigned short* __restrict__ Cb,
    const float* __restrict__ blo, const float* __restrict__ bhi,
    int M, int K, int ldc, int bsplit)
{
  __shared__ __align__(16) unsigned short As[128 * 64];
  __shared__ __align__(16) unsigned short Bs[128 * 64];
  const int t = threadIdx.x;
  const int w = t >> 6, lane = t & 63;
  const int tile_n = blockIdx.x * 128, tile_m = blockIdx.y * 128;   // x = N-tile: L2 share

  floatx4 acc[4][4] = {};

  // staging geometry: slot q = p*256 + w*64 + lane; row = q>>3; sj = q&7; gj = sj ^ (row&7)
  const int q = w * 64 + lane;          // 0..255 (p-invariant part)
  const int row0 = q >> 3;              // 0..31; row_p = row0 + p*32 (row&7 p-invariant)
  const int gj = (q & 7) ^ (row0 & 7);
  const unsigned short* gA0 = A  + (size_t)(tile_m + row0) * K + gj * 8;
  const unsigned short* gB0 = Bt + (size_t)(tile_n + row0) * K + gj * 8;

  const int wm = (w >> 1) * 64, wn = (w & 1) * 64;
  const int lrow = lane & 15, cg0 = (lane >> 4);
  const int sw = lrow & 7;              // row&7 of every fragment row this lane reads

  for (int k0 = 0; k0 < K; k0 += 64) {
#pragma unroll
    for (int p = 0; p < 4; p++) {
      __builtin_amdgcn_global_load_lds(
          (const __attribute__((address_space(1))) void*)(gA0 + (size_t)p * 32 * K),
          (__attribute__((address_space(3))) void*)(As + p * 2048 + w * 512), 16, 0, 0);
      __builtin_amdgcn_global_load_lds(
          (const __attribute__((address_space(1))) void*)(gB0 + (size_t)p * 32 * K),
          (__attribute__((address_space(3))) void*)(Bs + p * 2048 + w * 512), 16, 0, 0);
    }
    gA0 += 64; gB0 += 64;
    __syncthreads();
#pragma unroll
    for (int h = 0; h < 2; h++) {
      const int sc = (h * 4 + cg0) ^ sw;   // swizzled chunk slot
      bf16x8 a[4], b[4];
#pragma unroll
      for (int mi = 0; mi < 4; mi++)
        a[mi] = *(const bf16x8*)(As + (wm + mi * 16 + lrow) * 64 + sc * 8);
#pragma unroll
      for (int ni = 0; ni < 4; ni++)
        b[ni] = *(const bf16x8*)(Bs + (wn + ni * 16 + lrow) * 64 + sc * 8);
#pragma unroll
      for (int mi = 0; mi < 4; mi++)
#pragma unroll
        for (int ni = 0; ni < 4; ni++)
          acc[mi][ni] = __builtin_amdgcn_mfma_f32_16x16x32_bf16(a[mi], b[ni], acc[mi][ni], 0, 0, 0);
    }
    __syncthreads();
  }

  const int rbase = (lane >> 4) * 4;
#pragma unroll
  for (int mi = 0; mi < 4; mi++) {
#pragma unroll
    for (int r = 0; r < 4; r++) {
      int m = tile_m + wm + mi * 16 + rbase + r;
      if (m >= M) continue;
#pragma unroll
      for (int ni = 0; ni < 4; ni++) {
        int n = tile_n + wn + ni * 16 + lrow;
        float v = acc[mi][ni][r] + (n < bsplit ? blo[n] : bhi[n - bsplit]);
        if (MODE == 0) {
          Cf[(size_t)m * ldc + n] = v;
        } else if (MODE == 1) {
          Cf[(size_t)m * ldc + n] = v > 0.f ? v : expm1f(v);
        } else {  // all-bf16: xl = cols 0..1023, xr = cols 1024..2047
          Cb[(size_t)m * 2048 + n] = f2bf(v);
        }
      }
    }
  }
}

// ---------------- fused GATv2 edge phase + LayerNorm + ELU -> bf16 -------------
// block = dst node, 4 waves, wave == head. Each wave splits into two 32-lane halves
// processing ALTERNATING edges; lane owns 8 channels (16B) of its head. Per wave-iter:
// 2 edges, 1 uint4 load/lane, 5-step half-confined shfl score reduce, branchless
// online-softmax. Halves merged exactly via shfl_xor(.,32). LN: 5-step half reduce +
// cross-head LDS merge. Only half 0 stores.

__global__ __launch_bounds__(256) void gat_ln_kernel(
    const unsigned short* __restrict__ xlr,  // [N,2048] bf16: xl cols 0..1023, xr 1024..2047
    const float* __restrict__ att,           // [4,256]
    const int* __restrict__ csrsrc, const int* __restrict__ rstart,
    const float* __restrict__ bias,
    const float* __restrict__ lnw, const float* __restrict__ lnb,
    unsigned short* __restrict__ out)        // [N,1024] bf16
{
  const int d = blockIdx.x;
  const int t = threadIdx.x;
  const int lane = t & 63, wv = t >> 6;
  const int half = lane >> 5, j = lane & 31;
  const int c = wv * 256 + j * 8;      // 8 channels (16B) owned by this lane

  uint4 xru = *(const uint4*)(xlr + (size_t)d * 2048 + 1024 + c);
  floatx2 xr2[4] = {unpk2(xru.x), unpk2(xru.y), unpk2(xru.z), unpk2(xru.w)};
  float4 awa = *(const float4*)(att + c);
  float4 awb = *(const float4*)(att + c + 4);
  floatx2 aw2[4];
  aw2[0].x = awa.x; aw2[0].y = awa.y; aw2[1].x = awa.z; aw2[1].y = awa.w;
  aw2[2].x = awb.x; aw2[2].y = awb.y; aw2[3].x = awb.z; aw2[3].y = awb.w;

  int start = rstart[d], deg = rstart[d + 1] - start;

  float m = -3.0e38f, l = 0.f;
  floatx2 acc2[4] = {};

  for (int i = half; i < deg; i += 2) {
    int s = csrsrc[start + i];
    uint4 u = *(const uint4*)(xlr + (size_t)s * 2048 + c);
    floatx2 xs[4] = {unpk2(u.x), unpk2(u.y), unpk2(u.z), unpk2(u.w)};
    floatx2 P = {0.f, 0.f};
#pragma unroll
    for (int q = 0; q < 4; q++) {
      floatx2 tt = xs[q] + xr2[q];
      floatx2 lr = max2(tt, tt * NEG_SLOPE);
      P += lr * aw2[q];
    }
    float p = P.x + P.y;
#pragma unroll
    for (int mm = 16; mm >= 1; mm >>= 1) p += __shfl_xor(p, mm, 64);  // within half
    float mn = fmaxf(m, p);
    float sc = __expf(m - mn), pe = __expf(p - mn);
    floatx2 scv; scv.x = sc; scv.y = sc;
    floatx2 pev; pev.x = pe; pev.y = pe;
#pragma unroll
    for (int q = 0; q < 4; q++) acc2[q] = acc2[q] * scv + xs[q] * pev;
    l = l * sc + pe;
    m = mn;
  }

  // merge the two halves: lane j and j^32 hold the same channels, disjoint edge subsets
  float mo = __shfl_xor(m, 32, 64);
  float lo = __shfl_xor(l, 32, 64);
  float M = fmaxf(m, mo);
  float ea = __expf(m - M), eb = __expf(mo - M);   // empty half: ea/eb -> 0, safe
  float L = l * ea + lo * eb + 1e-16f;
  float rd = 1.f / L;
  float o[8];
#pragma unroll
  for (int q = 0; q < 4; q++) {
    float ax = acc2[q].x, ay = acc2[q].y;
    float bx = __shfl_xor(ax, 32, 64), by = __shfl_xor(ay, 32, 64);
    o[2 * q]     = (ax * ea + bx * eb) * rd;
    o[2 * q + 1] = (ay * ea + by * eb) * rd;
  }
  float4 bva = *(const float4*)(bias + c);
  float4 bvb = *(const float4*)(bias + c + 4);
  o[0] += bva.x; o[1] += bva.y; o[2] += bva.z; o[3] += bva.w;
  o[4] += bvb.x; o[5] += bvb.y; o[6] += bvb.z; o[7] += bvb.w;

  // LayerNorm over the 1024 channels held by this block (halves hold identical data)
  __shared__ float ws1[4], ws2[4];
  float s1 = 0.f, s2 = 0.f;
#pragma unroll
  for (int q = 0; q < 8; q++) { s1 += o[q]; s2 += o[q] * o[q]; }
#pragma unroll
  for (int mm = 16; mm >= 1; mm >>= 1) {
    s1 += __shfl_xor(s1, mm, 64);
    s2 += __shfl_xor(s2, mm, 64);
  }
  if (lane == 0) { ws1[wv] = s1; ws2[wv] = s2; }
  __syncthreads();
  float mean = (ws1[0] + ws1[1] + ws1[2] + ws1[3]) * (1.f / 1024.f);
  float var  = (ws2[0] + ws2[1] + ws2[2] + ws2[3]) * (1.f / 1024.f) - mean * mean;
  float rstd = rsqrtf(var + LN_EPS);

  if (half == 0) {
    float4 wva = *(const float4*)(lnw + c);
    float4 wvb = *(const float4*)(lnw + c + 4);
    float4 bba = *(const float4*)(lnb + c);
    float4 bbb = *(const float4*)(lnb + c + 4);
    float wz[8] = {wva.x, wva.y, wva.z, wva.w, wvb.x, wvb.y, wvb.z, wvb.w};
    float bz[8] = {bba.x, bba.y, bba.z, bba.w, bbb.x, bbb.y, bbb.z, bbb.w};
    float z[8];
#pragma unroll
    for (int q = 0; q < 8; q++) {
      float v = (o[q] - mean) * rstd * wz[q] + bz[q];
      z[q] = v > 0.f ? v : expm1f(v);
    }
    uint4 st;
    st.x = pk2bf(z[0], z[1]);
    st.y = pk2bf(z[2], z[3]);
    st.z = pk2bf(z[4], z[5]);
    st.w = pk2bf(z[6], z[7]);
    *(uint4*)(out + (size_t)d * 1024 + c) = st;
  }
}

// ---------------- final tiny GEMM: out[node][49] = h3 . w2t + b2 ----------------
// (R5 version: 10000 blocks x 64 threads — TLP beats per-block cleverness here.)

__global__ __launch_bounds__(64) void cls2_kernel(
    const float* __restrict__ h3, const float* __restrict__ w2t,
    const float* __restrict__ b2, float* __restrict__ out)
{
  __shared__ float row[256];
  int node = blockIdx.x, t = threadIdx.x;
  *(float4*)(row + t * 4) = *(const float4*)(h3 + (size_t)node * 256 + t * 4);
  __syncthreads();
  if (t < OUT_CH) {
    const float* wr = w2t + t * 256;
    float acc = b2[t];
#pragma unroll 4
    for (int k = 0; k < 256; k += 4) {
      float4 a = *(const float4*)(row + k);
      float4 wv = *(const float4*)(wr + k);
      acc += a.x * wv.x + a.y * wv.y + a.z * wv.z + a.w * wv.w;
    }
    out[node * OUT_CH + t] = acc;
  }
}

// ---------------- launch ----------------

extern "C" void kernel_launch(void* const* d_in, const int* in_sizes, int n_in,
                              void* d_out, int out_size, void* d_ws, size_t ws_size,
                              hipStream_t stream)
{
  const float* x       = (const float*)d_in[0];
  const int*   ei      = (const int*)d_in[1];
  const float* c1_wl   = (const float*)d_in[2];
  const float* c1_bl   = (const float*)d_in[3];
  const float* c1_wr   = (const float*)d_in[4];
  const float* c1_br   = (const float*)d_in[5];
  const float* c1_att  = (const float*)d_in[6];
  const float* c1_bias = (const float*)d_in[7];
  const float* ln1_w   = (const float*)d_in[8];
  const float* ln1_b   = (const float*)d_in[9];
  const float* c2_wl   = (const float*)d_in[10];
  const float* c2_bl   = (const float*)d_in[11];
  const float* c2_wr   = (const float*)d_in[12];
  const float* c2_br   = (const float*)d_in[13];
  const float* c2_att  = (const float*)d_in[14];
  const float* c2_bias = (const float*)d_in[15];
  const float* ln2_w   = (const float*)d_in[16];
  const float* ln2_b   = (const float*)d_in[17];
  const float* cls_w1  = (const float*)d_in[18];
  const float* cls_b1  = (const float*)d_in[19];
  const float* cls_w2  = (const float*)d_in[20];
  const float* cls_b2  = (const float*)d_in[21];

  const int* srcArr = ei;
  const int* dstArr = ei + N_EDGES;

  char* ws = (char*)d_ws;
  size_t off = 0;
  auto alloc = [&](size_t bytes) { void* p = ws + off; off += (bytes + 255) & ~(size_t)255; return p; };
  unsigned short* xa      = (unsigned short*)alloc((size_t)MPAD * K1PAD * 2);
  unsigned short* wt1     = (unsigned short*)alloc((size_t)2048 * K1PAD * 2);
  unsigned short* wt2     = (unsigned short*)alloc((size_t)2048 * 1024 * 2);
  unsigned short* wtc1    = (unsigned short*)alloc((size_t)256 * 1024 * 2);
  float*          w2t     = (float*)alloc((size_t)OUT_CH * 256 * 4);
  unsigned short* xlr     = (unsigned short*)alloc((size_t)N_NODES * 2048 * 2);  // bf16 xl|xr
  float*          h3      = (float*)alloc((size_t)N_NODES * 256 * 4);
  unsigned short* hb      = (unsigned short*)alloc((size_t)MPAD * 1024 * 2);
  int*            counts  = (int*)alloc(N_NODES * 4);
  int*            cursor  = (int*)alloc(N_NODES * 4);
  int*            rstart  = (int*)alloc((N_NODES + 1) * 4);
  int*            csrsrc  = (int*)alloc(E_TOT * 4);
  (void)in_sizes; (void)n_in; (void)out_size; (void)ws_size;

  // prep (cast_x also zeroes counts/cursor — replaces 2 memsets)
  cast_x_kernel<<<(N_NODES * K1PAD + 255) / 256, 256, 0, stream>>>(x, xa, counts, cursor);
  transpose_cast_kernel<<<dim3(64, 34), dim3(32, 8), 0, stream>>>(c1_wl, c1_wr, 1024, 1024, 1024, IN_CH, K1PAD, wt1);
  transpose_cast_kernel<<<dim3(64, 32), dim3(32, 8), 0, stream>>>(c2_wl, c2_wr, 1024, 1024, 1024, 1024, 1024, wt2);
  transpose_cast_kernel<<<dim3(8, 32), dim3(32, 8), 0, stream>>>(cls_w1, cls_w1, 256, 256, 256, 1024, 1024, wtc1);
  w2t_kernel<<<OUT_CH, 256, 0, stream>>>(cls_w2, w2t);

  // CSR by dst (payload = src node id)
  count_kernel<<<(E_TOT + 255) / 256, 256, 0, stream>>>(dstArr, counts);
  scan_kernel<<<1, 256, 0, stream>>>(counts, rstart);
  scatter_kernel<<<(E_TOT + 255) / 256, 256, 0, stream>>>(srcArr, dstArr, rstart, cursor, csrsrc);

  // layer 1
  gemm_bf16<2><<<dim3(16, 79), 256, 0, stream>>>(xa, wt1, nullptr, xlr, c1_bl, c1_br, N_NODES, K1PAD, 0, 1024);
  gat_ln_kernel<<<N_NODES, 256, 0, stream>>>(xlr, c1_att, csrsrc, rstart, c1_bias, ln1_w, ln1_b, hb);

  // layer 2
  gemm_bf16<2><<<dim3(16, 79), 256, 0, stream>>>(hb, wt2, nullptr, xlr, c2_bl, c2_br, N_NODES, 1024, 0, 1024);
  gat_ln_kernel<<<N_NODES, 256, 0, stream>>>(xlr, c2_att, csrsrc, rstart, c2_bias, ln2_w, ln2_b, hb);

  // classifier
  gemm_bf16<1><<<dim3(2, 79), 256, 0, stream>>>(hb, wtc1, h3, nullptr, cls_b1, cls_b1, N_NODES, 1024, 256, 1024);
  cls2_kernel<<<N_NODES, 64, 0, stream>>>(h3, w2t, cls_b2, (float*)d_out);
}

// Round 9
// 526.325 us; speedup vs baseline: 1.0451x; 1.0451x over previous
//
#include <hip/hip_runtime.h>
#include <stdint.h>

#define N_NODES 10000
#define N_EDGES 160000
#define E_TOT   170000   // edges + self loops
#define IN_CH   1030
#define HC      1024
#define OUT_CH  49
#define NEG_SLOPE 0.2f
#define LN_EPS 1e-5f

#define MPAD  10112   // 79 * 128
#define K1PAD 1088    // 17 * 64 (1030 padded to BK=64 multiple)

typedef __attribute__((ext_vector_type(8))) __bf16 bf16x8;
typedef __attribute__((ext_vector_type(4))) float floatx4;
typedef __attribute__((ext_vector_type(2))) float floatx2;

static __device__ __forceinline__ unsigned short f2bf(float f) {
  union { float f; uint32_t u; } v; v.f = f;
  uint32_t u = v.u;
  u += 0x7fffu + ((u >> 16) & 1u);   // round-to-nearest-even
  return (unsigned short)(u >> 16);
}
// unpack 2 bf16 (packed in a dword) -> 2 fp32
static __device__ __forceinline__ floatx2 unpk2(uint32_t u) {
  union { uint32_t i; float f; } a, b;
  a.i = u << 16; b.i = u & 0xffff0000u;
  floatx2 r; r.x = a.f; r.y = b.f; return r;
}
static __device__ __forceinline__ floatx2 max2(floatx2 a, floatx2 b) {
  floatx2 r; r.x = fmaxf(a.x, b.x); r.y = fmaxf(a.y, b.y); return r;
}

// ---------------- casts / transposes ----------------

__global__ void cast_x_kernel(const float* __restrict__ x, unsigned short* __restrict__ xa,
                              int* __restrict__ counts, int* __restrict__ cursor) {
  int idx = blockIdx.x * 256 + threadIdx.x;       // over N_NODES * K1PAD
  if (idx < N_NODES) { counts[idx] = 0; cursor[idx] = 0; }  // replaces 2 memsets
  if (idx >= N_NODES * K1PAD) return;
  int m = idx / K1PAD, k = idx - m * K1PAD;
  float v = (k < IN_CH) ? x[m * IN_CH + k] : 0.f;
  xa[idx] = f2bf(v);
}

// out[n*Kout + k] = (k < Kvalid ? W[k][n] : 0); W col picked from wa/wb by split
__global__ void transpose_cast_kernel(const float* __restrict__ wa, const float* __restrict__ wb,
                                      int split, int lda, int ldb,
                                      int Kvalid, int Kout, unsigned short* __restrict__ out) {
  __shared__ float tile[32][33];
  int n0 = blockIdx.x * 32, k0 = blockIdx.y * 32;
  int tx = threadIdx.x, ty = threadIdx.y;  // 32 x 8
#pragma unroll
  for (int i = 0; i < 4; i++) {
    int k = k0 + ty + i * 8;
    int n = n0 + tx;
    float v = 0.f;
    if (k < Kvalid) v = (n < split) ? wa[(size_t)k * lda + n] : wb[(size_t)k * ldb + (n - split)];
    tile[ty + i * 8][tx] = v;
  }
  __syncthreads();
#pragma unroll
  for (int i = 0; i < 4; i++) {
    int n = n0 + ty + i * 8;
    int k = k0 + tx;
    out[(size_t)n * Kout + k] = f2bf(tile[tx][ty + i * 8]);
  }
}

__global__ void w2t_kernel(const float* __restrict__ w2, float* __restrict__ out) {
  int o = blockIdx.x;            // 49 blocks
  int k = threadIdx.x;           // 256 threads
  out[o * 256 + k] = w2[k * OUT_CH + o];
}

// ---------------- CSR build (group edges by dst; store SRC ids directly) ----------------

__global__ void count_kernel(const int* __restrict__ dstArr, int* __restrict__ counts) {
  int e = blockIdx.x * 256 + threadIdx.x;
  if (e >= E_TOT) return;
  int d = (e < N_EDGES) ? dstArr[e] : (e - N_EDGES);
  atomicAdd(&counts[d], 1);
}

// two-level exclusive scan, 256 threads, 40 elems/thread serial
__global__ __launch_bounds__(256) void scan_kernel(const int* __restrict__ counts,
                                                   int* __restrict__ rstart) {
  __shared__ int sm[256];
  int t = threadIdx.x;
  int b0 = t * 40;
  int b1 = b0 + 40; if (b1 > N_NODES) b1 = N_NODES; if (b0 > N_NODES) b0 = N_NODES;
  int s = 0;
  for (int i = b0; i < b1; i++) s += counts[i];
  sm[t] = s; __syncthreads();
  for (int st = 1; st < 256; st <<= 1) {
    int add = (t >= st) ? sm[t - st] : 0;
    __syncthreads();
    sm[t] += add;
    __syncthreads();
  }
  int run = sm[t] - s;   // exclusive prefix of this thread's chunk
  for (int i = b0; i < b1; i++) { rstart[i] = run; run += counts[i]; }
  if (t == 255) rstart[N_NODES] = run;
}

__global__ void scatter_kernel(const int* __restrict__ srcArr, const int* __restrict__ dstArr,
                               const int* __restrict__ row_start,
                               int* __restrict__ cursor, int* __restrict__ csrsrc) {
  int e = blockIdx.x * 256 + threadIdx.x;
  if (e >= E_TOT) return;
  int d, sv;
  if (e < N_EDGES) { d = dstArr[e]; sv = srcArr[e]; }
  else { d = e - N_EDGES; sv = d; }     // self loop: src == dst
  int pos = atomicAdd(&cursor[d], 1);
  csrsrc[row_start[d] + pos] = sv;
}

// ---------------- bf16 MFMA GEMM: 128x128 tile, BK=64, XOR-swizzled LDS ----------------
// (R5/R7 single-buffer structure; dbuf regressed — see R6.)
// A: [M][K] bf16 (rows padded), Bt: [N][K] bf16. K must be a multiple of 64.
// LDS layout: slab of 128 rows x 64 cols; 16B chunk j of row r stored at slot (j ^ (r&7)).
// MODE 0: Cf = v+bias; MODE 1: ELU -> Cf; MODE 2: all-bf16 -> Cb[m*2048+n].
template <int MODE>
__global__ __launch_bounds__(256) void gemm_bf16(
    const unsigned short* __restrict__ A, const unsigned short* __restrict__ Bt,
    float* __restrict__ Cf, unsigned short* __restrict__ Cb,
    const float* __restrict__ blo, const float* __restrict__ bhi,
    int M, int K, int ldc, int bsplit)
{
  __shared__ __align__(16) unsigned short As[128 * 64];
  __shared__ __align__(16) unsigned short Bs[128 * 64];
  const int t = threadIdx.x;
  const int w = t >> 6, lane = t & 63;
  const int tile_n = blockIdx.x * 128, tile_m = blockIdx.y * 128;   // x = N-tile: L2 share

  floatx4 acc[4][4] = {};

  // staging geometry: slot q = p*256 + w*64 + lane; row = q>>3; sj = q&7; gj = sj ^ (row&7)
  const int q = w * 64 + lane;          // 0..255 (p-invariant part)
  const int row0 = q >> 3;              // 0..31; row_p = row0 + p*32 (row&7 p-invariant)
  const int gj = (q & 7) ^ (row0 & 7);
  const unsigned short* gA0 = A  + (size_t)(tile_m + row0) * K + gj * 8;
  const unsigned short* gB0 = Bt + (size_t)(tile_n + row0) * K + gj * 8;

  const int wm = (w >> 1) * 64, wn = (w & 1) * 64;
  const int lrow = lane & 15, cg0 = (lane >> 4);
  const int sw = lrow & 7;              // row&7 of every fragment row this lane reads

  for (int k0 = 0; k0 < K; k0 += 64) {
#pragma unroll
    for (int p = 0; p < 4; p++) {
      __builtin_amdgcn_global_load_lds(
          (const __attribute__((address_space(1))) void*)(gA0 + (size_t)p * 32 * K),
          (__attribute__((address_space(3))) void*)(As + p * 2048 + w * 512), 16, 0, 0);
      __builtin_amdgcn_global_load_lds(
          (const __attribute__((address_space(1))) void*)(gB0 + (size_t)p * 32 * K),
          (__attribute__((address_space(3))) void*)(Bs + p * 2048 + w * 512), 16, 0, 0);
    }
    gA0 += 64; gB0 += 64;
    __syncthreads();
#pragma unroll
    for (int h = 0; h < 2; h++) {
      const int sc = (h * 4 + cg0) ^ sw;   // swizzled chunk slot
      bf16x8 a[4], b[4];
#pragma unroll
      for (int mi = 0; mi < 4; mi++)
        a[mi] = *(const bf16x8*)(As + (wm + mi * 16 + lrow) * 64 + sc * 8);
#pragma unroll
      for (int ni = 0; ni < 4; ni++)
        b[ni] = *(const bf16x8*)(Bs + (wn + ni * 16 + lrow) * 64 + sc * 8);
#pragma unroll
      for (int mi = 0; mi < 4; mi++)
#pragma unroll
        for (int ni = 0; ni < 4; ni++)
          acc[mi][ni] = __builtin_amdgcn_mfma_f32_16x16x32_bf16(a[mi], b[ni], acc[mi][ni], 0, 0, 0);
    }
    __syncthreads();
  }

  const int rbase = (lane >> 4) * 4;
#pragma unroll
  for (int mi = 0; mi < 4; mi++) {
#pragma unroll
    for (int r = 0; r < 4; r++) {
      int m = tile_m + wm + mi * 16 + rbase + r;
      if (m >= M) continue;
#pragma unroll
      for (int ni = 0; ni < 4; ni++) {
        int n = tile_n + wn + ni * 16 + lrow;
        float v = acc[mi][ni][r] + (n < bsplit ? blo[n] : bhi[n - bsplit]);
        if (MODE == 0) {
          Cf[(size_t)m * ldc + n] = v;
        } else if (MODE == 1) {
          Cf[(size_t)m * ldc + n] = v > 0.f ? v : expm1f(v);
        } else {  // all-bf16: xl = cols 0..1023, xr = cols 1024..2047
          Cb[(size_t)m * 2048 + n] = f2bf(v);
        }
      }
    }
  }
}

// ---------------- fused GATv2 edge phase + LayerNorm + ELU -> bf16 -------------
// R7 structure (the proven local optimum: 4 ch/lane, full-wave 6-step reduce,
// wave==head, all 4 waves walk all edges) with a 4-EDGE UNROLL: 4 gathers in
// flight, 4 interleaved shuffle chains, online-softmax update amortized 1:4.

__global__ __launch_bounds__(256) void gat_ln_kernel(
    const unsigned short* __restrict__ xlr,  // [N,2048] bf16: xl cols 0..1023, xr 1024..2047
    const float* __restrict__ att,           // [4,256]
    const int* __restrict__ csrsrc, const int* __restrict__ rstart,
    const float* __restrict__ bias,
    const float* __restrict__ lnw, const float* __restrict__ lnb,
    unsigned short* __restrict__ out)        // [N,1024] bf16
{
  const int d = blockIdx.x;
  const int t = threadIdx.x;
  const int lane = t & 63, wv = t >> 6;
  const int c = wv * 256 + lane * 4;   // 4 channels of head wv

  uint2 xru = *(const uint2*)(xlr + (size_t)d * 2048 + 1024 + c);
  floatx2 xrA = unpk2(xru.x), xrB = unpk2(xru.y);
  float4 aw4 = *(const float4*)(att + c);
  floatx2 awA; awA.x = aw4.x; awA.y = aw4.y;
  floatx2 awB; awB.x = aw4.z; awB.y = aw4.w;
  const unsigned short* xbase = xlr + c;

  int start = rstart[d], deg = rstart[d + 1] - start;

  float m = -3.0e38f, l = 0.f;
  floatx2 accA = {0.f, 0.f}, accB = {0.f, 0.f};

  int i = 0;
  for (; i + 4 <= deg; i += 4) {
    int s0 = csrsrc[start + i],     s1 = csrsrc[start + i + 1];
    int s2 = csrsrc[start + i + 2], s3 = csrsrc[start + i + 3];
    uint2 u0 = *(const uint2*)(xbase + (size_t)s0 * 2048);
    uint2 u1 = *(const uint2*)(xbase + (size_t)s1 * 2048);
    uint2 u2 = *(const uint2*)(xbase + (size_t)s2 * 2048);
    uint2 u3 = *(const uint2*)(xbase + (size_t)s3 * 2048);
    floatx2 x0A = unpk2(u0.x), x0B = unpk2(u0.y);
    floatx2 x1A = unpk2(u1.x), x1B = unpk2(u1.y);
    floatx2 x2A = unpk2(u2.x), x2B = unpk2(u2.y);
    floatx2 x3A = unpk2(u3.x), x3B = unpk2(u3.y);
    floatx2 t0A = x0A + xrA, t0B = x0B + xrB;
    floatx2 t1A = x1A + xrA, t1B = x1B + xrB;
    floatx2 t2A = x2A + xrA, t2B = x2B + xrB;
    floatx2 t3A = x3A + xrA, t3B = x3B + xrB;
    floatx2 l0A = max2(t0A, t0A * NEG_SLOPE), l0B = max2(t0B, t0B * NEG_SLOPE);
    floatx2 l1A = max2(t1A, t1A * NEG_SLOPE), l1B = max2(t1B, t1B * NEG_SLOPE);
    floatx2 l2A = max2(t2A, t2A * NEG_SLOPE), l2B = max2(t2B, t2B * NEG_SLOPE);
    floatx2 l3A = max2(t3A, t3A * NEG_SLOPE), l3B = max2(t3B, t3B * NEG_SLOPE);
    floatx2 P0 = l0A * awA; P0 += l0B * awB;
    floatx2 P1 = l1A * awA; P1 += l1B * awB;
    floatx2 P2 = l2A * awA; P2 += l2B * awB;
    floatx2 P3 = l3A * awA; P3 += l3B * awB;
    float p0 = P0.x + P0.y, p1 = P1.x + P1.y;
    float p2 = P2.x + P2.y, p3 = P3.x + P3.y;
#pragma unroll
    for (int mm = 32; mm >= 1; mm >>= 1) {
      p0 += __shfl_xor(p0, mm, 64);
      p1 += __shfl_xor(p1, mm, 64);
      p2 += __shfl_xor(p2, mm, 64);
      p3 += __shfl_xor(p3, mm, 64);
    }
    float mx = fmaxf(fmaxf(p0, p1), fmaxf(p2, p3));
    if (mx > m) {                        // wave-uniform branch (p,m uniform after reduce)
      float sc = __expf(m - mx);
      floatx2 scv; scv.x = sc; scv.y = sc;
      accA *= scv; accB *= scv; l *= sc;
      m = mx;
    }
    float pe0 = __expf(p0 - m), pe1 = __expf(p1 - m);
    float pe2 = __expf(p2 - m), pe3 = __expf(p3 - m);
    floatx2 v0; v0.x = pe0; v0.y = pe0;
    floatx2 v1; v1.x = pe1; v1.y = pe1;
    floatx2 v2; v2.x = pe2; v2.y = pe2;
    floatx2 v3; v3.x = pe3; v3.y = pe3;
    accA += x0A * v0; accA += x1A * v1; accA += x2A * v2; accA += x3A * v3;
    accB += x0B * v0; accB += x1B * v1; accB += x2B * v2; accB += x3B * v3;
    l += pe0 + pe1 + pe2 + pe3;
  }
  for (; i < deg; i++) {
    int s0 = csrsrc[start + i];
    uint2 u0 = *(const uint2*)(xbase + (size_t)s0 * 2048);
    floatx2 x0A = unpk2(u0.x), x0B = unpk2(u0.y);
    floatx2 t0A = x0A + xrA, t0B = x0B + xrB;
    floatx2 l0A = max2(t0A, t0A * NEG_SLOPE), l0B = max2(t0B, t0B * NEG_SLOPE);
    floatx2 P0 = l0A * awA; P0 += l0B * awB;
    float p0 = P0.x + P0.y;
#pragma unroll
    for (int mm = 32; mm >= 1; mm >>= 1) p0 += __shfl_xor(p0, mm, 64);
    if (p0 > m) {
      float sc = __expf(m - p0);
      floatx2 scv; scv.x = sc; scv.y = sc;
      accA *= scv; accB *= scv; l *= sc;
      m = p0;
    }
    float pe0 = __expf(p0 - m);
    floatx2 pe0v; pe0v.x = pe0; pe0v.y = pe0;
    accA += x0A * pe0v;
    accB += x0B * pe0v;
    l += pe0;
  }

  float rd = 1.f / (l + 1e-16f);
  float4 bv = *(const float4*)(bias + c);
  float o0 = accA.x * rd + bv.x, o1 = accA.y * rd + bv.y;
  float o2 = accB.x * rd + bv.z, o3 = accB.y * rd + bv.w;

  // LayerNorm over the 1024 channels held by this block
  __shared__ float ws1[4], ws2[4];
  float s1 = o0 + o1 + o2 + o3;
  float s2 = o0 * o0 + o1 * o1 + o2 * o2 + o3 * o3;
#pragma unroll
  for (int mm = 32; mm >= 1; mm >>= 1) {
    s1 += __shfl_xor(s1, mm, 64);
    s2 += __shfl_xor(s2, mm, 64);
  }
  if (lane == 0) { ws1[wv] = s1; ws2[wv] = s2; }
  __syncthreads();
  float mean = (ws1[0] + ws1[1] + ws1[2] + ws1[3]) * (1.f / 1024.f);
  float var  = (ws2[0] + ws2[1] + ws2[2] + ws2[3]) * (1.f / 1024.f) - mean * mean;
  float rstd = rsqrtf(var + LN_EPS);
  float4 wv4 = *(const float4*)(lnw + c);
  float4 bb  = *(const float4*)(lnb + c);
  float z0 = (o0 - mean) * rstd * wv4.x + bb.x; z0 = z0 > 0.f ? z0 : expm1f(z0);
  float z1 = (o1 - mean) * rstd * wv4.y + bb.y; z1 = z1 > 0.f ? z1 : expm1f(z1);
  float z2 = (o2 - mean) * rstd * wv4.z + bb.z; z2 = z2 > 0.f ? z2 : expm1f(z2);
  float z3 = (o3 - mean) * rstd * wv4.w + bb.w; z3 = z3 > 0.f ? z3 : expm1f(z3);
  ushort4 u;
  u.x = f2bf(z0); u.y = f2bf(z1); u.z = f2bf(z2); u.w = f2bf(z3);
  *(ushort4*)(out + (size_t)d * 1024 + c) = u;
}

// ---------------- final tiny GEMM: out[node][49] = h3 . w2t + b2 ----------------
// (R5 version: 10000 blocks x 64 threads — TLP beats per-block cleverness here.)

__global__ __launch_bounds__(64) void cls2_kernel(
    const float* __restrict__ h3, const float* __restrict__ w2t,
    const float* __restrict__ b2, float* __restrict__ out)
{
  __shared__ float row[256];
  int node = blockIdx.x, t = threadIdx.x;
  *(float4*)(row + t * 4) = *(const float4*)(h3 + (size_t)node * 256 + t * 4);
  __syncthreads();
  if (t < OUT_CH) {
    const float* wr = w2t + t * 256;
    float acc = b2[t];
#pragma unroll 4
    for (int k = 0; k < 256; k += 4) {
      float4 a = *(const float4*)(row + k);
      float4 wv = *(const float4*)(wr + k);
      acc += a.x * wv.x + a.y * wv.y + a.z * wv.z + a.w * wv.w;
    }
    out[node * OUT_CH + t] = acc;
  }
}

// ---------------- launch ----------------

extern "C" void kernel_launch(void* const* d_in, const int* in_sizes, int n_in,
                              void* d_out, int out_size, void* d_ws, size_t ws_size,
                              hipStream_t stream)
{
  const float* x       = (const float*)d_in[0];
  const int*   ei      = (const int*)d_in[1];
  const float* c1_wl   = (const float*)d_in[2];
  const float* c1_bl   = (const float*)d_in[3];
  const float* c1_wr   = (const float*)d_in[4];
  const float* c1_br   = (const float*)d_in[5];
  const float* c1_att  = (const float*)d_in[6];
  const float* c1_bias = (const float*)d_in[7];
  const float* ln1_w   = (const float*)d_in[8];
  const float* ln1_b   = (const float*)d_in[9];
  const float* c2_wl   = (const float*)d_in[10];
  const float* c2_bl   = (const float*)d_in[11];
  const float* c2_wr   = (const float*)d_in[12];
  const float* c2_br   = (const float*)d_in[13];
  const float* c2_att  = (const float*)d_in[14];
  const float* c2_bias = (const float*)d_in[15];
  const float* ln2_w   = (const float*)d_in[16];
  const float* ln2_b   = (const float*)d_in[17];
  const float* cls_w1  = (const float*)d_in[18];
  const float* cls_b1  = (const float*)d_in[19];
  const float* cls_w2  = (const float*)d_in[20];
  const float* cls_b2  = (const float*)d_in[21];

  const int* srcArr = ei;
  const int* dstArr = ei + N_EDGES;

  char* ws = (char*)d_ws;
  size_t off = 0;
  auto alloc = [&](size_t bytes) { void* p = ws + off; off += (bytes + 255) & ~(size_t)255; return p; };
  unsigned short* xa      = (unsigned short*)alloc((size_t)MPAD * K1PAD * 2);
  unsigned short* wt1     = (unsigned short*)alloc((size_t)2048 * K1PAD * 2);
  unsigned short* wt2     = (unsigned short*)alloc((size_t)2048 * 1024 * 2);
  unsigned short* wtc1    = (unsigned short*)alloc((size_t)256 * 1024 * 2);
  float*          w2t     = (float*)alloc((size_t)OUT_CH * 256 * 4);
  unsigned short* xlr     = (unsigned short*)alloc((size_t)N_NODES * 2048 * 2);  // bf16 xl|xr
  float*          h3      = (float*)alloc((size_t)N_NODES * 256 * 4);
  unsigned short* hb      = (unsigned short*)alloc((size_t)MPAD * 1024 * 2);
  int*            counts  = (int*)alloc(N_NODES * 4);
  int*            cursor  = (int*)alloc(N_NODES * 4);
  int*            rstart  = (int*)alloc((N_NODES + 1) * 4);
  int*            csrsrc  = (int*)alloc(E_TOT * 4);
  (void)in_sizes; (void)n_in; (void)out_size; (void)ws_size;

  // prep (cast_x also zeroes counts/cursor — replaces 2 memsets)
  cast_x_kernel<<<(N_NODES * K1PAD + 255) / 256, 256, 0, stream>>>(x, xa, counts, cursor);
  transpose_cast_kernel<<<dim3(64, 34), dim3(32, 8), 0, stream>>>(c1_wl, c1_wr, 1024, 1024, 1024, IN_CH, K1PAD, wt1);
  transpose_cast_kernel<<<dim3(64, 32), dim3(32, 8), 0, stream>>>(c2_wl, c2_wr, 1024, 1024, 1024, 1024, 1024, wt2);
  transpose_cast_kernel<<<dim3(8, 32), dim3(32, 8), 0, stream>>>(cls_w1, cls_w1, 256, 256, 256, 1024, 1024, wtc1);
  w2t_kernel<<<OUT_CH, 256, 0, stream>>>(cls_w2, w2t);

  // CSR by dst (payload = src node id)
  count_kernel<<<(E_TOT + 255) / 256, 256, 0, stream>>>(dstArr, counts);
  scan_kernel<<<1, 256, 0, stream>>>(counts, rstart);
  scatter_kernel<<<(E_TOT + 255) / 256, 256, 0, stream>>>(srcArr, dstArr, rstart, cursor, csrsrc);

  // layer 1
  gemm_bf16<2><<<dim3(16, 79), 256, 0, stream>>>(xa, wt1, nullptr, xlr, c1_bl, c1_br, N_NODES, K1PAD, 0, 1024);
  gat_ln_kernel<<<N_NODES, 256, 0, stream>>>(xlr, c1_att, csrsrc, rstart, c1_bias, ln1_w, ln1_b, hb);

  // layer 2
  gemm_bf16<2><<<dim3(16, 79), 256, 0, stream>>>(hb, wt2, nullptr, xlr, c2_bl, c2_br, N_NODES, 1024, 0, 1024);
  gat_ln_kernel<<<N_NODES, 256, 0, stream>>>(xlr, c2_att, csrsrc, rstart, c2_bias, ln2_w, ln2_b, hb);

  // classifier
  gemm_bf16<1><<<dim3(2, 79), 256, 0, stream>>>(hb, wtc1, h3, nullptr, cls_b1, cls_b1, N_NODES, 1024, 256, 1024);
  cls2_kernel<<<N_NODES, 64, 0, stream>>>(h3, w2t, cls_b2, (float*)d_out);
}

// Round 10
// 507.792 us; speedup vs baseline: 1.0832x; 1.0365x over previous
//
#include <hip/hip_runtime.h>
#include <stdint.h>

#define N_NODES 10000
#define N_EDGES 160000
#define E_TOT   170000   // edges + self loops
#define IN_CH   1030
#define HC      1024
#define OUT_CH  49
#define NEG_SLOPE 0.2f
#define LN_EPS 1e-5f

#define MPAD  10112   // 79 * 128
#define K1PAD 1088    // 17 * 64 (1030 padded to BK=64 multiple)

typedef __attribute__((ext_vector_type(8))) __bf16 bf16x8;
typedef __attribute__((ext_vector_type(4))) float floatx4;
typedef __attribute__((ext_vector_type(2))) float floatx2;

static __device__ __forceinline__ unsigned short f2bf(float f) {
  union { float f; uint32_t u; } v; v.f = f;
  uint32_t u = v.u;
  u += 0x7fffu + ((u >> 16) & 1u);   // round-to-nearest-even
  return (unsigned short)(u >> 16);
}
// unpack 2 bf16 (packed in a dword) -> 2 fp32
static __device__ __forceinline__ floatx2 unpk2(uint32_t u) {
  union { uint32_t i; float f; } a, b;
  a.i = u << 16; b.i = u & 0xffff0000u;
  floatx2 r; r.x = a.f; r.y = b.f; return r;
}
static __device__ __forceinline__ floatx2 max2(floatx2 a, floatx2 b) {
  floatx2 r; r.x = fmaxf(a.x, b.x); r.y = fmaxf(a.y, b.y); return r;
}

// ---------------- casts / transposes ----------------

__global__ void cast_x_kernel(const float* __restrict__ x, unsigned short* __restrict__ xa,
                              int* __restrict__ counts, int* __restrict__ cursor) {
  int idx = blockIdx.x * 256 + threadIdx.x;       // over N_NODES * K1PAD
  if (idx < N_NODES) { counts[idx] = 0; cursor[idx] = 0; }  // replaces 2 memsets
  if (idx >= N_NODES * K1PAD) return;
  int m = idx / K1PAD, k = idx - m * K1PAD;
  float v = (k < IN_CH) ? x[m * IN_CH + k] : 0.f;
  xa[idx] = f2bf(v);
}

// out[n*Kout + k] = (k < Kvalid ? W[k][n] : 0); W col picked from wa/wb by split
__global__ void transpose_cast_kernel(const float* __restrict__ wa, const float* __restrict__ wb,
                                      int split, int lda, int ldb,
                                      int Kvalid, int Kout, unsigned short* __restrict__ out) {
  __shared__ float tile[32][33];
  int n0 = blockIdx.x * 32, k0 = blockIdx.y * 32;
  int tx = threadIdx.x, ty = threadIdx.y;  // 32 x 8
#pragma unroll
  for (int i = 0; i < 4; i++) {
    int k = k0 + ty + i * 8;
    int n = n0 + tx;
    float v = 0.f;
    if (k < Kvalid) v = (n < split) ? wa[(size_t)k * lda + n] : wb[(size_t)k * ldb + (n - split)];
    tile[ty + i * 8][tx] = v;
  }
  __syncthreads();
#pragma unroll
  for (int i = 0; i < 4; i++) {
    int n = n0 + ty + i * 8;
    int k = k0 + tx;
    out[(size_t)n * Kout + k] = f2bf(tile[tx][ty + i * 8]);
  }
}

__global__ void w2t_kernel(const float* __restrict__ w2, float* __restrict__ out) {
  int o = blockIdx.x;            // 49 blocks
  int k = threadIdx.x;           // 256 threads
  out[o * 256 + k] = w2[k * OUT_CH + o];
}

// ---------------- CSR build (group edges by dst; store SRC ids directly) ----------------

__global__ void count_kernel(const int* __restrict__ dstArr, int* __restrict__ counts) {
  int e = blockIdx.x * 256 + threadIdx.x;
  if (e >= E_TOT) return;
  int d = (e < N_EDGES) ? dstArr[e] : (e - N_EDGES);
  atomicAdd(&counts[d], 1);
}

// two-level exclusive scan, 256 threads, 40 elems/thread serial
__global__ __launch_bounds__(256) void scan_kernel(const int* __restrict__ counts,
                                                   int* __restrict__ rstart) {
  __shared__ int sm[256];
  int t = threadIdx.x;
  int b0 = t * 40;
  int b1 = b0 + 40; if (b1 > N_NODES) b1 = N_NODES; if (b0 > N_NODES) b0 = N_NODES;
  int s = 0;
  for (int i = b0; i < b1; i++) s += counts[i];
  sm[t] = s; __syncthreads();
  for (int st = 1; st < 256; st <<= 1) {
    int add = (t >= st) ? sm[t - st] : 0;
    __syncthreads();
    sm[t] += add;
    __syncthreads();
  }
  int run = sm[t] - s;   // exclusive prefix of this thread's chunk
  for (int i = b0; i < b1; i++) { rstart[i] = run; run += counts[i]; }
  if (t == 255) rstart[N_NODES] = run;
}

__global__ void scatter_kernel(const int* __restrict__ srcArr, const int* __restrict__ dstArr,
                               const int* __restrict__ row_start,
                               int* __restrict__ cursor, int* __restrict__ csrsrc) {
  int e = blockIdx.x * 256 + threadIdx.x;
  if (e >= E_TOT) return;
  int d, sv;
  if (e < N_EDGES) { d = dstArr[e]; sv = srcArr[e]; }
  else { d = e - N_EDGES; sv = d; }     // self loop: src == dst
  int pos = atomicAdd(&cursor[d], 1);
  csrsrc[row_start[d] + pos] = sv;
}

// ---------------- bf16 MFMA GEMM: 128x128 tile, BK=64, XOR-swizzled LDS ----------------
// R9 inner loop unchanged. New: KC is a COMPILE-TIME template param (staging strides
// p*32*KC fold into SGPR bases, freeing address VGPRs) and __launch_bounds__(256,4)
// forces 4 waves/SIMD residency (4 blocks/CU; budget 128 regs/wave = 64 AGPR acc +
// <=64 arch VGPR). R9 cycle math: 22% MfmaUtil == 2 blocks/CU resident — register
// footprint, not LDS, was the limiter.
// MODE 0: Cf = v+bias; MODE 1: ELU -> Cf; MODE 2: all-bf16 -> Cb[m*2048+n].
template <int MODE, int KC>
__global__ __launch_bounds__(256, 4) void gemm_bf16(
    const unsigned short* __restrict__ A, const unsigned short* __restrict__ Bt,
    float* __restrict__ Cf, unsigned short* __restrict__ Cb,
    const float* __restrict__ blo, const float* __restrict__ bhi,
    int M, int ldc, int bsplit)
{
  __shared__ __align__(16) unsigned short As[128 * 64];
  __shared__ __align__(16) unsigned short Bs[128 * 64];
  const int t = threadIdx.x;
  const int w = t >> 6, lane = t & 63;
  const int tile_n = blockIdx.x * 128, tile_m = blockIdx.y * 128;   // x = N-tile: L2 share

  floatx4 acc[4][4] = {};

  // staging geometry: slot q = p*256 + w*64 + lane; row = q>>3; sj = q&7; gj = sj ^ (row&7)
  const int q = w * 64 + lane;          // 0..255 (p-invariant part)
  const int row0 = q >> 3;              // 0..31; row_p = row0 + p*32 (row&7 p-invariant)
  const int gj = (q & 7) ^ (row0 & 7);
  const unsigned short* gA0 = A  + (size_t)(tile_m + row0) * KC + gj * 8;
  const unsigned short* gB0 = Bt + (size_t)(tile_n + row0) * KC + gj * 8;

  const int wm = (w >> 1) * 64, wn = (w & 1) * 64;
  const int lrow = lane & 15, cg0 = (lane >> 4);
  const int sw = lrow & 7;              // row&7 of every fragment row this lane reads

#pragma unroll 1
  for (int k0 = 0; k0 < KC; k0 += 64) {
#pragma unroll
    for (int p = 0; p < 4; p++) {
      __builtin_amdgcn_global_load_lds(
          (const __attribute__((address_space(1))) void*)(gA0 + p * 32 * KC),
          (__attribute__((address_space(3))) void*)(As + p * 2048 + w * 512), 16, 0, 0);
      __builtin_amdgcn_global_load_lds(
          (const __attribute__((address_space(1))) void*)(gB0 + p * 32 * KC),
          (__attribute__((address_space(3))) void*)(Bs + p * 2048 + w * 512), 16, 0, 0);
    }
    gA0 += 64; gB0 += 64;
    __syncthreads();
#pragma unroll
    for (int h = 0; h < 2; h++) {
      const int sc = (h * 4 + cg0) ^ sw;   // swizzled chunk slot
      bf16x8 a[4], b[4];
#pragma unroll
      for (int mi = 0; mi < 4; mi++)
        a[mi] = *(const bf16x8*)(As + (wm + mi * 16 + lrow) * 64 + sc * 8);
#pragma unroll
      for (int ni = 0; ni < 4; ni++)
        b[ni] = *(const bf16x8*)(Bs + (wn + ni * 16 + lrow) * 64 + sc * 8);
#pragma unroll
      for (int mi = 0; mi < 4; mi++)
#pragma unroll
        for (int ni = 0; ni < 4; ni++)
          acc[mi][ni] = __builtin_amdgcn_mfma_f32_16x16x32_bf16(a[mi], b[ni], acc[mi][ni], 0, 0, 0);
    }
    __syncthreads();
  }

  const int rbase = (lane >> 4) * 4;
#pragma unroll
  for (int mi = 0; mi < 4; mi++) {
#pragma unroll
    for (int r = 0; r < 4; r++) {
      int m = tile_m + wm + mi * 16 + rbase + r;
      if (m >= M) continue;
#pragma unroll
      for (int ni = 0; ni < 4; ni++) {
        int n = tile_n + wn + ni * 16 + lrow;
        float v = acc[mi][ni][r] + (n < bsplit ? blo[n] : bhi[n - bsplit]);
        if (MODE == 0) {
          Cf[(size_t)m * ldc + n] = v;
        } else if (MODE == 1) {
          Cf[(size_t)m * ldc + n] = v > 0.f ? v : expm1f(v);
        } else {  // all-bf16: xl = cols 0..1023, xr = cols 1024..2047
          Cb[(size_t)m * 2048 + n] = f2bf(v);
        }
      }
    }
  }
}

// ---------------- fused GATv2 edge phase + LayerNorm + ELU -> bf16 -------------
// R7 structure (4 ch/lane, full-wave 6-step reduce, wave==head, all 4 waves walk
// all edges) with the R9 4-EDGE UNROLL: 4 gathers in flight, 4 interleaved shuffle
// chains, online-softmax update amortized 1:4.

__global__ __launch_bounds__(256) void gat_ln_kernel(
    const unsigned short* __restrict__ xlr,  // [N,2048] bf16: xl cols 0..1023, xr 1024..2047
    const float* __restrict__ att,           // [4,256]
    const int* __restrict__ csrsrc, const int* __restrict__ rstart,
    const float* __restrict__ bias,
    const float* __restrict__ lnw, const float* __restrict__ lnb,
    unsigned short* __restrict__ out)        // [N,1024] bf16
{
  const int d = blockIdx.x;
  const int t = threadIdx.x;
  const int lane = t & 63, wv = t >> 6;
  const int c = wv * 256 + lane * 4;   // 4 channels of head wv

  uint2 xru = *(const uint2*)(xlr + (size_t)d * 2048 + 1024 + c);
  floatx2 xrA = unpk2(xru.x), xrB = unpk2(xru.y);
  float4 aw4 = *(const float4*)(att + c);
  floatx2 awA; awA.x = aw4.x; awA.y = aw4.y;
  floatx2 awB; awB.x = aw4.z; awB.y = aw4.w;
  const unsigned short* xbase = xlr + c;

  int start = rstart[d], deg = rstart[d + 1] - start;

  float m = -3.0e38f, l = 0.f;
  floatx2 accA = {0.f, 0.f}, accB = {0.f, 0.f};

  int i = 0;
  for (; i + 4 <= deg; i += 4) {
    int s0 = csrsrc[start + i],     s1 = csrsrc[start + i + 1];
    int s2 = csrsrc[start + i + 2], s3 = csrsrc[start + i + 3];
    uint2 u0 = *(const uint2*)(xbase + (size_t)s0 * 2048);
    uint2 u1 = *(const uint2*)(xbase + (size_t)s1 * 2048);
    uint2 u2 = *(const uint2*)(xbase + (size_t)s2 * 2048);
    uint2 u3 = *(const uint2*)(xbase + (size_t)s3 * 2048);
    floatx2 x0A = unpk2(u0.x), x0B = unpk2(u0.y);
    floatx2 x1A = unpk2(u1.x), x1B = unpk2(u1.y);
    floatx2 x2A = unpk2(u2.x), x2B = unpk2(u2.y);
    floatx2 x3A = unpk2(u3.x), x3B = unpk2(u3.y);
    floatx2 t0A = x0A + xrA, t0B = x0B + xrB;
    floatx2 t1A = x1A + xrA, t1B = x1B + xrB;
    floatx2 t2A = x2A + xrA, t2B = x2B + xrB;
    floatx2 t3A = x3A + xrA, t3B = x3B + xrB;
    floatx2 l0A = max2(t0A, t0A * NEG_SLOPE), l0B = max2(t0B, t0B * NEG_SLOPE);
    floatx2 l1A = max2(t1A, t1A * NEG_SLOPE), l1B = max2(t1B, t1B * NEG_SLOPE);
    floatx2 l2A = max2(t2A, t2A * NEG_SLOPE), l2B = max2(t2B, t2B * NEG_SLOPE);
    floatx2 l3A = max2(t3A, t3A * NEG_SLOPE), l3B = max2(t3B, t3B * NEG_SLOPE);
    floatx2 P0 = l0A * awA; P0 += l0B * awB;
    floatx2 P1 = l1A * awA; P1 += l1B * awB;
    floatx2 P2 = l2A * awA; P2 += l2B * awB;
    floatx2 P3 = l3A * awA; P3 += l3B * awB;
    float p0 = P0.x + P0.y, p1 = P1.x + P1.y;
    float p2 = P2.x + P2.y, p3 = P3.x + P3.y;
#pragma unroll
    for (int mm = 32; mm >= 1; mm >>= 1) {
      p0 += __shfl_xor(p0, mm, 64);
      p1 += __shfl_xor(p1, mm, 64);
      p2 += __shfl_xor(p2, mm, 64);
      p3 += __shfl_xor(p3, mm, 64);
    }
    float mx = fmaxf(fmaxf(p0, p1), fmaxf(p2, p3));
    if (mx > m) {                        // wave-uniform branch (p,m uniform after reduce)
      float sc = __expf(m - mx);
      floatx2 scv; scv.x = sc; scv.y = sc;
      accA *= scv; accB *= scv; l *= sc;
      m = mx;
    }
    float pe0 = __expf(p0 - m), pe1 = __expf(p1 - m);
    float pe2 = __expf(p2 - m), pe3 = __expf(p3 - m);
    floatx2 v0; v0.x = pe0; v0.y = pe0;
    floatx2 v1; v1.x = pe1; v1.y = pe1;
    floatx2 v2; v2.x = pe2; v2.y = pe2;
    floatx2 v3; v3.x = pe3; v3.y = pe3;
    accA += x0A * v0; accA += x1A * v1; accA += x2A * v2; accA += x3A * v3;
    accB += x0B * v0; accB += x1B * v1; accB += x2B * v2; accB += x3B * v3;
    l += pe0 + pe1 + pe2 + pe3;
  }
  for (; i < deg; i++) {
    int s0 = csrsrc[start + i];
    uint2 u0 = *(const uint2*)(xbase + (size_t)s0 * 2048);
    floatx2 x0A = unpk2(u0.x), x0B = unpk2(u0.y);
    floatx2 t0A = x0A + xrA, t0B = x0B + xrB;
    floatx2 l0A = max2(t0A, t0A * NEG_SLOPE), l0B = max2(t0B, t0B * NEG_SLOPE);
    floatx2 P0 = l0A * awA; P0 += l0B * awB;
    float p0 = P0.x + P0.y;
#pragma unroll
    for (int mm = 32; mm >= 1; mm >>= 1) p0 += __shfl_xor(p0, mm, 64);
    if (p0 > m) {
      float sc = __expf(m - p0);
      floatx2 scv; scv.x = sc; scv.y = sc;
      accA *= scv; accB *= scv; l *= sc;
      m = p0;
    }
    float pe0 = __expf(p0 - m);
    floatx2 pe0v; pe0v.x = pe0; pe0v.y = pe0;
    accA += x0A * pe0v;
    accB += x0B * pe0v;
    l += pe0;
  }

  float rd = 1.f / (l + 1e-16f);
  float4 bv = *(const float4*)(bias + c);
  float o0 = accA.x * rd + bv.x, o1 = accA.y * rd + bv.y;
  float o2 = accB.x * rd + bv.z, o3 = accB.y * rd + bv.w;

  // LayerNorm over the 1024 channels held by this block
  __shared__ float ws1[4], ws2[4];
  float s1 = o0 + o1 + o2 + o3;
  float s2 = o0 * o0 + o1 * o1 + o2 * o2 + o3 * o3;
#pragma unroll
  for (int mm = 32; mm >= 1; mm >>= 1) {
    s1 += __shfl_xor(s1, mm, 64);
    s2 += __shfl_xor(s2, mm, 64);
  }
  if (lane == 0) { ws1[wv] = s1; ws2[wv] = s2; }
  __syncthreads();
  float mean = (ws1[0] + ws1[1] + ws1[2] + ws1[3]) * (1.f / 1024.f);
  float var  = (ws2[0] + ws2[1] + ws2[2] + ws2[3]) * (1.f / 1024.f) - mean * mean;
  float rstd = rsqrtf(var + LN_EPS);
  float4 wv4 = *(const float4*)(lnw + c);
  float4 bb  = *(const float4*)(lnb + c);
  float z0 = (o0 - mean) * rstd * wv4.x + bb.x; z0 = z0 > 0.f ? z0 : expm1f(z0);
  float z1 = (o1 - mean) * rstd * wv4.y + bb.y; z1 = z1 > 0.f ? z1 : expm1f(z1);
  float z2 = (o2 - mean) * rstd * wv4.z + bb.z; z2 = z2 > 0.f ? z2 : expm1f(z2);
  float z3 = (o3 - mean) * rstd * wv4.w + bb.w; z3 = z3 > 0.f ? z3 : expm1f(z3);
  ushort4 u;
  u.x = f2bf(z0); u.y = f2bf(z1); u.z = f2bf(z2); u.w = f2bf(z3);
  *(ushort4*)(out + (size_t)d * 1024 + c) = u;
}

// ---------------- final tiny GEMM: out[node][49] = h3 . w2t + b2 ----------------
// (R5 version: 10000 blocks x 64 threads — TLP beats per-block cleverness here.)

__global__ __launch_bounds__(64) void cls2_kernel(
    const float* __restrict__ h3, const float* __restrict__ w2t,
    const float* __restrict__ b2, float* __restrict__ out)
{
  __shared__ float row[256];
  int node = blockIdx.x, t = threadIdx.x;
  *(float4*)(row + t * 4) = *(const float4*)(h3 + (size_t)node * 256 + t * 4);
  __syncthreads();
  if (t < OUT_CH) {
    const float* wr = w2t + t * 256;
    float acc = b2[t];
#pragma unroll 4
    for (int k = 0; k < 256; k += 4) {
      float4 a = *(const float4*)(row + k);
      float4 wv = *(const float4*)(wr + k);
      acc += a.x * wv.x + a.y * wv.y + a.z * wv.z + a.w * wv.w;
    }
    out[node * OUT_CH + t] = acc;
  }
}

// ---------------- launch ----------------

extern "C" void kernel_launch(void* const* d_in, const int* in_sizes, int n_in,
                              void* d_out, int out_size, void* d_ws, size_t ws_size,
                              hipStream_t stream)
{
  const float* x       = (const float*)d_in[0];
  const int*   ei      = (const int*)d_in[1];
  const float* c1_wl   = (const float*)d_in[2];
  const float* c1_bl   = (const float*)d_in[3];
  const float* c1_wr   = (const float*)d_in[4];
  const float* c1_br   = (const float*)d_in[5];
  const float* c1_att  = (const float*)d_in[6];
  const float* c1_bias = (const float*)d_in[7];
  const float* ln1_w   = (const float*)d_in[8];
  const float* ln1_b   = (const float*)d_in[9];
  const float* c2_wl   = (const float*)d_in[10];
  const float* c2_bl   = (const float*)d_in[11];
  const float* c2_wr   = (const float*)d_in[12];
  const float* c2_br   = (const float*)d_in[13];
  const float* c2_att  = (const float*)d_in[14];
  const float* c2_bias = (const float*)d_in[15];
  const float* ln2_w   = (const float*)d_in[16];
  const float* ln2_b   = (const float*)d_in[17];
  const float* cls_w1  = (const float*)d_in[18];
  const float* cls_b1  = (const float*)d_in[19];
  const float* cls_w2  = (const float*)d_in[20];
  const float* cls_b2  = (const float*)d_in[21];

  const int* srcArr = ei;
  const int* dstArr = ei + N_EDGES;

  char* ws = (char*)d_ws;
  size_t off = 0;
  auto alloc = [&](size_t bytes) { void* p = ws + off; off += (bytes + 255) & ~(size_t)255; return p; };
  unsigned short* xa      = (unsigned short*)alloc((size_t)MPAD * K1PAD * 2);
  unsigned short* wt1     = (unsigned short*)alloc((size_t)2048 * K1PAD * 2);
  unsigned short* wt2     = (unsigned short*)alloc((size_t)2048 * 1024 * 2);
  unsigned short* wtc1    = (unsigned short*)alloc((size_t)256 * 1024 * 2);
  float*          w2t     = (float*)alloc((size_t)OUT_CH * 256 * 4);
  unsigned short* xlr     = (unsigned short*)alloc((size_t)N_NODES * 2048 * 2);  // bf16 xl|xr
  float*          h3      = (float*)alloc((size_t)N_NODES * 256 * 4);
  unsigned short* hb      = (unsigned short*)alloc((size_t)MPAD * 1024 * 2);
  int*            counts  = (int*)alloc(N_NODES * 4);
  int*            cursor  = (int*)alloc(N_NODES * 4);
  int*            rstart  = (int*)alloc((N_NODES + 1) * 4);
  int*            csrsrc  = (int*)alloc(E_TOT * 4);
  (void)in_sizes; (void)n_in; (void)out_size; (void)ws_size;

  // prep (cast_x also zeroes counts/cursor — replaces 2 memsets)
  cast_x_kernel<<<(N_NODES * K1PAD + 255) / 256, 256, 0, stream>>>(x, xa, counts, cursor);
  transpose_cast_kernel<<<dim3(64, 34), dim3(32, 8), 0, stream>>>(c1_wl, c1_wr, 1024, 1024, 1024, IN_CH, K1PAD, wt1);
  transpose_cast_kernel<<<dim3(64, 32), dim3(32, 8), 0, stream>>>(c2_wl, c2_wr, 1024, 1024, 1024, 1024, 1024, wt2);
  transpose_cast_kernel<<<dim3(8, 32), dim3(32, 8), 0, stream>>>(cls_w1, cls_w1, 256, 256, 256, 1024, 1024, wtc1);
  w2t_kernel<<<OUT_CH, 256, 0, stream>>>(cls_w2, w2t);

  // CSR by dst (payload = src node id)
  count_kernel<<<(E_TOT + 255) / 256, 256, 0, stream>>>(dstArr, counts);
  scan_kernel<<<1, 256, 0, stream>>>(counts, rstart);
  scatter_kernel<<<(E_TOT + 255) / 256, 256, 0, stream>>>(srcArr, dstArr, rstart, cursor, csrsrc);

  // layer 1
  gemm_bf16<2, K1PAD><<<dim3(16, 79), 256, 0, stream>>>(xa, wt1, nullptr, xlr, c1_bl, c1_br, N_NODES, 0, 1024);
  gat_ln_kernel<<<N_NODES, 256, 0, stream>>>(xlr, c1_att, csrsrc, rstart, c1_bias, ln1_w, ln1_b, hb);

  // layer 2
  gemm_bf16<2, 1024><<<dim3(16, 79), 256, 0, stream>>>(hb, wt2, nullptr, xlr, c2_bl, c2_br, N_NODES, 0, 1024);
  gat_ln_kernel<<<N_NODES, 256, 0, stream>>>(xlr, c2_att, csrsrc, rstart, c2_bias, ln2_w, ln2_b, hb);

  // classifier
  gemm_bf16<1, 1024><<<dim3(2, 79), 256, 0, stream>>>(hb, wtc1, h3, nullptr, cls_b1, cls_b1, N_NODES, 256, 1024);
  cls2_kernel<<<N_NODES, 64, 0, stream>>>(h3, w2t, cls_b2, (float*)d_out);
}

// Round 11
// 499.595 us; speedup vs baseline: 1.1010x; 1.0164x over previous
//
#include <hip/hip_runtime.h>
#include <stdint.h>

#define N_NODES 10000
#define N_EDGES 160000
#define E_TOT   170000   // edges + self loops
#define IN_CH   1030
#define HC      1024
#define OUT_CH  49
#define NEG_SLOPE 0.2f
#define LN_EPS 1e-5f

#define MPAD  10112   // 79 * 128
#define K1PAD 1088    // 17 * 64 (1030 padded to BK=64 multiple)

typedef __attribute__((ext_vector_type(8))) __bf16 bf16x8;
typedef __attribute__((ext_vector_type(4))) float floatx4;
typedef __attribute__((ext_vector_type(2))) float floatx2;

static __device__ __forceinline__ unsigned short f2bf(float f) {
  union { float f; uint32_t u; } v; v.f = f;
  uint32_t u = v.u;
  u += 0x7fffu + ((u >> 16) & 1u);   // round-to-nearest-even
  return (unsigned short)(u >> 16);
}
// unpack 2 bf16 (packed in a dword) -> 2 fp32
static __device__ __forceinline__ floatx2 unpk2(uint32_t u) {
  union { uint32_t i; float f; } a, b;
  a.i = u << 16; b.i = u & 0xffff0000u;
  floatx2 r; r.x = a.f; r.y = b.f; return r;
}
static __device__ __forceinline__ floatx2 max2(floatx2 a, floatx2 b) {
  floatx2 r; r.x = fmaxf(a.x, b.x); r.y = fmaxf(a.y, b.y); return r;
}

// ---------------- casts / transposes ----------------

__global__ void cast_x_kernel(const float* __restrict__ x, unsigned short* __restrict__ xa,
                              int* __restrict__ counts, int* __restrict__ cursor) {
  int idx = blockIdx.x * 256 + threadIdx.x;       // over N_NODES * K1PAD
  if (idx < N_NODES) { counts[idx] = 0; cursor[idx] = 0; }  // replaces 2 memsets
  if (idx >= N_NODES * K1PAD) return;
  int m = idx / K1PAD, k = idx - m * K1PAD;
  float v = (k < IN_CH) ? x[m * IN_CH + k] : 0.f;
  xa[idx] = f2bf(v);
}

// out[n*Kout + k] = (k < Kvalid ? W[k][n] : 0); W col picked from wa/wb by split
__global__ void transpose_cast_kernel(const float* __restrict__ wa, const float* __restrict__ wb,
                                      int split, int lda, int ldb,
                                      int Kvalid, int Kout, unsigned short* __restrict__ out) {
  __shared__ float tile[32][33];
  int n0 = blockIdx.x * 32, k0 = blockIdx.y * 32;
  int tx = threadIdx.x, ty = threadIdx.y;  // 32 x 8
#pragma unroll
  for (int i = 0; i < 4; i++) {
    int k = k0 + ty + i * 8;
    int n = n0 + tx;
    float v = 0.f;
    if (k < Kvalid) v = (n < split) ? wa[(size_t)k * lda + n] : wb[(size_t)k * ldb + (n - split)];
    tile[ty + i * 8][tx] = v;
  }
  __syncthreads();
#pragma unroll
  for (int i = 0; i < 4; i++) {
    int n = n0 + ty + i * 8;
    int k = k0 + tx;
    out[(size_t)n * Kout + k] = f2bf(tile[tx][ty + i * 8]);
  }
}

// ---------------- CSR build (group edges by dst; store SRC ids directly) ----------------

__global__ void count_kernel(const int* __restrict__ dstArr, int* __restrict__ counts) {
  int e = blockIdx.x * 256 + threadIdx.x;
  if (e >= E_TOT) return;
  int d = (e < N_EDGES) ? dstArr[e] : (e - N_EDGES);
  atomicAdd(&counts[d], 1);
}

// two-level exclusive scan, 256 threads, 40 elems/thread serial
__global__ __launch_bounds__(256) void scan_kernel(const int* __restrict__ counts,
                                                   int* __restrict__ rstart) {
  __shared__ int sm[256];
  int t = threadIdx.x;
  int b0 = t * 40;
  int b1 = b0 + 40; if (b1 > N_NODES) b1 = N_NODES; if (b0 > N_NODES) b0 = N_NODES;
  int s = 0;
  for (int i = b0; i < b1; i++) s += counts[i];
  sm[t] = s; __syncthreads();
  for (int st = 1; st < 256; st <<= 1) {
    int add = (t >= st) ? sm[t - st] : 0;
    __syncthreads();
    sm[t] += add;
    __syncthreads();
  }
  int run = sm[t] - s;   // exclusive prefix of this thread's chunk
  for (int i = b0; i < b1; i++) { rstart[i] = run; run += counts[i]; }
  if (t == 255) rstart[N_NODES] = run;
}

__global__ void scatter_kernel(const int* __restrict__ srcArr, const int* __restrict__ dstArr,
                               const int* __restrict__ row_start,
                               int* __restrict__ cursor, int* __restrict__ csrsrc) {
  int e = blockIdx.x * 256 + threadIdx.x;
  if (e >= E_TOT) return;
  int d, sv;
  if (e < N_EDGES) { d = dstArr[e]; sv = srcArr[e]; }
  else { d = e - N_EDGES; sv = d; }     // self loop: src == dst
  int pos = atomicAdd(&cursor[d], 1);
  csrsrc[row_start[d] + pos] = sv;
}

// ---------------- bf16 MFMA GEMM: 128x128 tile, BK=64, XOR-swizzled LDS ----------------
// KC compile-time (staging strides fold to SGPRs); __launch_bounds__(256,4) forces
// 4 waves/SIMD residency (R10: MfmaUtil 22->~2x, gemm dropped out of top-5).
// MODE 0: Cf = v+bias; MODE 1: ELU -> Cf; MODE 2: all-bf16 -> Cb[m*2048+n].
template <int MODE, int KC>
__global__ __launch_bounds__(256, 4) void gemm_bf16(
    const unsigned short* __restrict__ A, const unsigned short* __restrict__ Bt,
    float* __restrict__ Cf, unsigned short* __restrict__ Cb,
    const float* __restrict__ blo, const float* __restrict__ bhi,
    int M, int ldc, int bsplit)
{
  __shared__ __align__(16) unsigned short As[128 * 64];
  __shared__ __align__(16) unsigned short Bs[128 * 64];
  const int t = threadIdx.x;
  const int w = t >> 6, lane = t & 63;
  const int tile_n = blockIdx.x * 128, tile_m = blockIdx.y * 128;   // x = N-tile: L2 share

  floatx4 acc[4][4] = {};

  // staging geometry: slot q = p*256 + w*64 + lane; row = q>>3; sj = q&7; gj = sj ^ (row&7)
  const int q = w * 64 + lane;          // 0..255 (p-invariant part)
  const int row0 = q >> 3;              // 0..31; row_p = row0 + p*32 (row&7 p-invariant)
  const int gj = (q & 7) ^ (row0 & 7);
  const unsigned short* gA0 = A  + (size_t)(tile_m + row0) * KC + gj * 8;
  const unsigned short* gB0 = Bt + (size_t)(tile_n + row0) * KC + gj * 8;

  const int wm = (w >> 1) * 64, wn = (w & 1) * 64;
  const int lrow = lane & 15, cg0 = (lane >> 4);
  const int sw = lrow & 7;              // row&7 of every fragment row this lane reads

#pragma unroll 1
  for (int k0 = 0; k0 < KC; k0 += 64) {
#pragma unroll
    for (int p = 0; p < 4; p++) {
      __builtin_amdgcn_global_load_lds(
          (const __attribute__((address_space(1))) void*)(gA0 + p * 32 * KC),
          (__attribute__((address_space(3))) void*)(As + p * 2048 + w * 512), 16, 0, 0);
      __builtin_amdgcn_global_load_lds(
          (const __attribute__((address_space(1))) void*)(gB0 + p * 32 * KC),
          (__attribute__((address_space(3))) void*)(Bs + p * 2048 + w * 512), 16, 0, 0);
    }
    gA0 += 64; gB0 += 64;
    __syncthreads();
#pragma unroll
    for (int h = 0; h < 2; h++) {
      const int sc = (h * 4 + cg0) ^ sw;   // swizzled chunk slot
      bf16x8 a[4], b[4];
#pragma unroll
      for (int mi = 0; mi < 4; mi++)
        a[mi] = *(const bf16x8*)(As + (wm + mi * 16 + lrow) * 64 + sc * 8);
#pragma unroll
      for (int ni = 0; ni < 4; ni++)
        b[ni] = *(const bf16x8*)(Bs + (wn + ni * 16 + lrow) * 64 + sc * 8);
#pragma unroll
      for (int mi = 0; mi < 4; mi++)
#pragma unroll
        for (int ni = 0; ni < 4; ni++)
          acc[mi][ni] = __builtin_amdgcn_mfma_f32_16x16x32_bf16(a[mi], b[ni], acc[mi][ni], 0, 0, 0);
    }
    __syncthreads();
  }

  const int rbase = (lane >> 4) * 4;
#pragma unroll
  for (int mi = 0; mi < 4; mi++) {
#pragma unroll
    for (int r = 0; r < 4; r++) {
      int m = tile_m + wm + mi * 16 + rbase + r;
      if (m >= M) continue;
#pragma unroll
      for (int ni = 0; ni < 4; ni++) {
        int n = tile_n + wn + ni * 16 + lrow;
        float v = acc[mi][ni][r] + (n < bsplit ? blo[n] : bhi[n - bsplit]);
        if (MODE == 0) {
          Cf[(size_t)m * ldc + n] = v;
        } else if (MODE == 1) {
          Cf[(size_t)m * ldc + n] = v > 0.f ? v : expm1f(v);
        } else {  // all-bf16: xl = cols 0..1023, xr = cols 1024..2047
          Cb[(size_t)m * 2048 + n] = f2bf(v);
        }
      }
    }
  }
}

// ---------------- fused GATv2 edge phase + LayerNorm + ELU -> bf16 -------------
// R7 structure (4 ch/lane, full-wave 6-step reduce, wave==head, all 4 waves walk
// all edges) with the R9 4-EDGE UNROLL: 4 gathers in flight, 4 interleaved shuffle
// chains, online-softmax update amortized 1:4.

__global__ __launch_bounds__(256) void gat_ln_kernel(
    const unsigned short* __restrict__ xlr,  // [N,2048] bf16: xl cols 0..1023, xr 1024..2047
    const float* __restrict__ att,           // [4,256]
    const int* __restrict__ csrsrc, const int* __restrict__ rstart,
    const float* __restrict__ bias,
    const float* __restrict__ lnw, const float* __restrict__ lnb,
    unsigned short* __restrict__ out)        // [N,1024] bf16
{
  const int d = blockIdx.x;
  const int t = threadIdx.x;
  const int lane = t & 63, wv = t >> 6;
  const int c = wv * 256 + lane * 4;   // 4 channels of head wv

  uint2 xru = *(const uint2*)(xlr + (size_t)d * 2048 + 1024 + c);
  floatx2 xrA = unpk2(xru.x), xrB = unpk2(xru.y);
  float4 aw4 = *(const float4*)(att + c);
  floatx2 awA; awA.x = aw4.x; awA.y = aw4.y;
  floatx2 awB; awB.x = aw4.z; awB.y = aw4.w;
  const unsigned short* xbase = xlr + c;

  int start = rstart[d], deg = rstart[d + 1] - start;

  float m = -3.0e38f, l = 0.f;
  floatx2 accA = {0.f, 0.f}, accB = {0.f, 0.f};

  int i = 0;
  for (; i + 4 <= deg; i += 4) {
    int s0 = csrsrc[start + i],     s1 = csrsrc[start + i + 1];
    int s2 = csrsrc[start + i + 2], s3 = csrsrc[start + i + 3];
    uint2 u0 = *(const uint2*)(xbase + (size_t)s0 * 2048);
    uint2 u1 = *(const uint2*)(xbase + (size_t)s1 * 2048);
    uint2 u2 = *(const uint2*)(xbase + (size_t)s2 * 2048);
    uint2 u3 = *(const uint2*)(xbase + (size_t)s3 * 2048);
    floatx2 x0A = unpk2(u0.x), x0B = unpk2(u0.y);
    floatx2 x1A = unpk2(u1.x), x1B = unpk2(u1.y);
    floatx2 x2A = unpk2(u2.x), x2B = unpk2(u2.y);
    floatx2 x3A = unpk2(u3.x), x3B = unpk2(u3.y);
    floatx2 t0A = x0A + xrA, t0B = x0B + xrB;
    floatx2 t1A = x1A + xrA, t1B = x1B + xrB;
    floatx2 t2A = x2A + xrA, t2B = x2B + xrB;
    floatx2 t3A = x3A + xrA, t3B = x3B + xrB;
    floatx2 l0A = max2(t0A, t0A * NEG_SLOPE), l0B = max2(t0B, t0B * NEG_SLOPE);
    floatx2 l1A = max2(t1A, t1A * NEG_SLOPE), l1B = max2(t1B, t1B * NEG_SLOPE);
    floatx2 l2A = max2(t2A, t2A * NEG_SLOPE), l2B = max2(t2B, t2B * NEG_SLOPE);
    floatx2 l3A = max2(t3A, t3A * NEG_SLOPE), l3B = max2(t3B, t3B * NEG_SLOPE);
    floatx2 P0 = l0A * awA; P0 += l0B * awB;
    floatx2 P1 = l1A * awA; P1 += l1B * awB;
    floatx2 P2 = l2A * awA; P2 += l2B * awB;
    floatx2 P3 = l3A * awA; P3 += l3B * awB;
    float p0 = P0.x + P0.y, p1 = P1.x + P1.y;
    float p2 = P2.x + P2.y, p3 = P3.x + P3.y;
#pragma unroll
    for (int mm = 32; mm >= 1; mm >>= 1) {
      p0 += __shfl_xor(p0, mm, 64);
      p1 += __shfl_xor(p1, mm, 64);
      p2 += __shfl_xor(p2, mm, 64);
      p3 += __shfl_xor(p3, mm, 64);
    }
    float mx = fmaxf(fmaxf(p0, p1), fmaxf(p2, p3));
    if (mx > m) {                        // wave-uniform branch (p,m uniform after reduce)
      float sc = __expf(m - mx);
      floatx2 scv; scv.x = sc; scv.y = sc;
      accA *= scv; accB *= scv; l *= sc;
      m = mx;
    }
    float pe0 = __expf(p0 - m), pe1 = __expf(p1 - m);
    float pe2 = __expf(p2 - m), pe3 = __expf(p3 - m);
    floatx2 v0; v0.x = pe0; v0.y = pe0;
    floatx2 v1; v1.x = pe1; v1.y = pe1;
    floatx2 v2; v2.x = pe2; v2.y = pe2;
    floatx2 v3; v3.x = pe3; v3.y = pe3;
    accA += x0A * v0; accA += x1A * v1; accA += x2A * v2; accA += x3A * v3;
    accB += x0B * v0; accB += x1B * v1; accB += x2B * v2; accB += x3B * v3;
    l += pe0 + pe1 + pe2 + pe3;
  }
  for (; i < deg; i++) {
    int s0 = csrsrc[start + i];
    uint2 u0 = *(const uint2*)(xbase + (size_t)s0 * 2048);
    floatx2 x0A = unpk2(u0.x), x0B = unpk2(u0.y);
    floatx2 t0A = x0A + xrA, t0B = x0B + xrB;
    floatx2 l0A = max2(t0A, t0A * NEG_SLOPE), l0B = max2(t0B, t0B * NEG_SLOPE);
    floatx2 P0 = l0A * awA; P0 += l0B * awB;
    float p0 = P0.x + P0.y;
#pragma unroll
    for (int mm = 32; mm >= 1; mm >>= 1) p0 += __shfl_xor(p0, mm, 64);
    if (p0 > m) {
      float sc = __expf(m - p0);
      floatx2 scv; scv.x = sc; scv.y = sc;
      accA *= scv; accB *= scv; l *= sc;
      m = p0;
    }
    float pe0 = __expf(p0 - m);
    floatx2 pe0v; pe0v.x = pe0; pe0v.y = pe0;
    accA += x0A * pe0v;
    accB += x0B * pe0v;
    l += pe0;
  }

  float rd = 1.f / (l + 1e-16f);
  float4 bv = *(const float4*)(bias + c);
  float o0 = accA.x * rd + bv.x, o1 = accA.y * rd + bv.y;
  float o2 = accB.x * rd + bv.z, o3 = accB.y * rd + bv.w;

  // LayerNorm over the 1024 channels held by this block
  __shared__ float ws1[4], ws2[4];
  float s1 = o0 + o1 + o2 + o3;
  float s2 = o0 * o0 + o1 * o1 + o2 * o2 + o3 * o3;
#pragma unroll
  for (int mm = 32; mm >= 1; mm >>= 1) {
    s1 += __shfl_xor(s1, mm, 64);
    s2 += __shfl_xor(s2, mm, 64);
  }
  if (lane == 0) { ws1[wv] = s1; ws2[wv] = s2; }
  __syncthreads();
  float mean = (ws1[0] + ws1[1] + ws1[2] + ws1[3]) * (1.f / 1024.f);
  float var  = (ws2[0] + ws2[1] + ws2[2] + ws2[3]) * (1.f / 1024.f) - mean * mean;
  float rstd = rsqrtf(var + LN_EPS);
  float4 wv4 = *(const float4*)(lnw + c);
  float4 bb  = *(const float4*)(lnb + c);
  float z0 = (o0 - mean) * rstd * wv4.x + bb.x; z0 = z0 > 0.f ? z0 : expm1f(z0);
  float z1 = (o1 - mean) * rstd * wv4.y + bb.y; z1 = z1 > 0.f ? z1 : expm1f(z1);
  float z2 = (o2 - mean) * rstd * wv4.z + bb.z; z2 = z2 > 0.f ? z2 : expm1f(z2);
  float z3 = (o3 - mean) * rstd * wv4.w + bb.w; z3 = z3 > 0.f ? z3 : expm1f(z3);
  ushort4 u;
  u.x = f2bf(z0); u.y = f2bf(z1); u.z = f2bf(z2); u.w = f2bf(z3);
  *(ushort4*)(out + (size_t)d * 1024 + c) = u;
}

// ---------------- final tiny GEMM: out[node][49] = h3 . w2 + b2 ----------------
// 10000 blocks x 64 threads (proven TLP shape). w2 read in NATIVE k-major [256][49]
// layout: at step k lanes o=0..48 hit consecutive addresses (1 coalesced ~196B segment
// vs 49 cache lines in the old per-lane-row layout which thrashed L1). row[k] is
// wave-uniform -> LDS broadcast. 4 independent partial sums break the fma chain.

__global__ __launch_bounds__(64) void cls2_kernel(
    const float* __restrict__ h3, const float* __restrict__ w2,
    const float* __restrict__ b2, float* __restrict__ out)
{
  __shared__ float row[256];
  int node = blockIdx.x, t = threadIdx.x;
  *(float4*)(row + t * 4) = *(const float4*)(h3 + (size_t)node * 256 + t * 4);
  __syncthreads();
  if (t < OUT_CH) {
    float a0 = 0.f, a1 = 0.f, a2 = 0.f, a3 = 0.f;
#pragma unroll 4
    for (int k = 0; k < 256; k += 4) {
      float4 r = *(const float4*)(row + k);       // uniform addr -> LDS broadcast
      a0 += r.x * w2[(k + 0) * OUT_CH + t];       // lanes consecutive -> coalesced
      a1 += r.y * w2[(k + 1) * OUT_CH + t];
      a2 += r.z * w2[(k + 2) * OUT_CH + t];
      a3 += r.w * w2[(k + 3) * OUT_CH + t];
    }
    out[node * OUT_CH + t] = (a0 + a1) + (a2 + a3) + b2[t];
  }
}

// ---------------- launch ----------------

extern "C" void kernel_launch(void* const* d_in, const int* in_sizes, int n_in,
                              void* d_out, int out_size, void* d_ws, size_t ws_size,
                              hipStream_t stream)
{
  const float* x       = (const float*)d_in[0];
  const int*   ei      = (const int*)d_in[1];
  const float* c1_wl   = (const float*)d_in[2];
  const float* c1_bl   = (const float*)d_in[3];
  const float* c1_wr   = (const float*)d_in[4];
  const float* c1_br   = (const float*)d_in[5];
  const float* c1_att  = (const float*)d_in[6];
  const float* c1_bias = (const float*)d_in[7];
  const float* ln1_w   = (const float*)d_in[8];
  const float* ln1_b   = (const float*)d_in[9];
  const float* c2_wl   = (const float*)d_in[10];
  const float* c2_bl   = (const float*)d_in[11];
  const float* c2_wr   = (const float*)d_in[12];
  const float* c2_br   = (const float*)d_in[13];
  const float* c2_att  = (const float*)d_in[14];
  const float* c2_bias = (const float*)d_in[15];
  const float* ln2_w   = (const float*)d_in[16];
  const float* ln2_b   = (const float*)d_in[17];
  const float* cls_w1  = (const float*)d_in[18];
  const float* cls_b1  = (const float*)d_in[19];
  const float* cls_w2  = (const float*)d_in[20];
  const float* cls_b2  = (const float*)d_in[21];

  const int* srcArr = ei;
  const int* dstArr = ei + N_EDGES;

  char* ws = (char*)d_ws;
  size_t off = 0;
  auto alloc = [&](size_t bytes) { void* p = ws + off; off += (bytes + 255) & ~(size_t)255; return p; };
  unsigned short* xa      = (unsigned short*)alloc((size_t)MPAD * K1PAD * 2);
  unsigned short* wt1     = (unsigned short*)alloc((size_t)2048 * K1PAD * 2);
  unsigned short* wt2     = (unsigned short*)alloc((size_t)2048 * 1024 * 2);
  unsigned short* wtc1    = (unsigned short*)alloc((size_t)256 * 1024 * 2);
  unsigned short* xlr     = (unsigned short*)alloc((size_t)N_NODES * 2048 * 2);  // bf16 xl|xr
  float*          h3      = (float*)alloc((size_t)N_NODES * 256 * 4);
  unsigned short* hb      = (unsigned short*)alloc((size_t)MPAD * 1024 * 2);
  int*            counts  = (int*)alloc(N_NODES * 4);
  int*            cursor  = (int*)alloc(N_NODES * 4);
  int*            rstart  = (int*)alloc((N_NODES + 1) * 4);
  int*            csrsrc  = (int*)alloc(E_TOT * 4);
  (void)in_sizes; (void)n_in; (void)out_size; (void)ws_size;

  // prep (cast_x also zeroes counts/cursor — replaces 2 memsets)
  cast_x_kernel<<<(N_NODES * K1PAD + 255) / 256, 256, 0, stream>>>(x, xa, counts, cursor);
  transpose_cast_kernel<<<dim3(64, 34), dim3(32, 8), 0, stream>>>(c1_wl, c1_wr, 1024, 1024, 1024, IN_CH, K1PAD, wt1);
  transpose_cast_kernel<<<dim3(64, 32), dim3(32, 8), 0, stream>>>(c2_wl, c2_wr, 1024, 1024, 1024, 1024, 1024, wt2);
  transpose_cast_kernel<<<dim3(8, 32), dim3(32, 8), 0, stream>>>(cls_w1, cls_w1, 256, 256, 256, 1024, 1024, wtc1);

  // CSR by dst (payload = src node id)
  count_kernel<<<(E_TOT + 255) / 256, 256, 0, stream>>>(dstArr, counts);
  scan_kernel<<<1, 256, 0, stream>>>(counts, rstart);
  scatter_kernel<<<(E_TOT + 255) / 256, 256, 0, stream>>>(srcArr, dstArr, rstart, cursor, csrsrc);

  // layer 1
  gemm_bf16<2, K1PAD><<<dim3(16, 79), 256, 0, stream>>>(xa, wt1, nullptr, xlr, c1_bl, c1_br, N_NODES, 0, 1024);
  gat_ln_kernel<<<N_NODES, 256, 0, stream>>>(xlr, c1_att, csrsrc, rstart, c1_bias, ln1_w, ln1_b, hb);

  // layer 2
  gemm_bf16<2, 1024><<<dim3(16, 79), 256, 0, stream>>>(hb, wt2, nullptr, xlr, c2_bl, c2_br, N_NODES, 0, 1024);
  gat_ln_kernel<<<N_NODES, 256, 0, stream>>>(xlr, c2_att, csrsrc, rstart, c2_bias, ln2_w, ln2_b, hb);

  // classifier
  gemm_bf16<1, 1024><<<dim3(2, 79), 256, 0, stream>>>(hb, wtc1, h3, nullptr, cls_b1, cls_b1, N_NODES, 256, 1024);
  cls2_kernel<<<N_NODES, 64, 0, stream>>>(h3, cls_w2, cls_b2, (float*)d_out);
}

// Round 13
// 472.605 us; speedup vs baseline: 1.1639x; 1.0571x over previous
//
#include <hip/hip_runtime.h>
#include <stdint.h>

#define N_NODES 10000
#define N_EDGES 160000
#define E_TOT   170000   // edges + self loops
#define IN_CH   1030
#define HC      1024
#define OUT_CH  49
#define NEG_SLOPE 0.2f
#define LN_EPS 1e-5f
#define LOG2E 1.4426950408889634f

#define MPAD  10112   // 79 * 128
#define K1PAD 1088    // 17 * 64 (1030 padded to BK=64 multiple)

typedef __attribute__((ext_vector_type(8))) __bf16 bf16x8;
typedef __attribute__((ext_vector_type(4))) float floatx4;
typedef __attribute__((ext_vector_type(2))) float floatx2;
typedef _Float16 h2 __attribute__((ext_vector_type(2)));

static __device__ __forceinline__ unsigned short f2bf(float f) {
  union { float f; uint32_t u; } v; v.f = f;
  uint32_t u = v.u;
  u += 0x7fffu + ((u >> 16) & 1u);   // round-to-nearest-even
  return (unsigned short)(u >> 16);
}
static __device__ __forceinline__ unsigned short f2h(float f) {
  _Float16 h = (_Float16)f;
  union { _Float16 h; unsigned short u; } v; v.h = h; return v.u;
}
static __device__ __forceinline__ h2 bits2h2(uint32_t u) {
  union { uint32_t i; h2 h; } v; v.i = u; return v.h;
}
static __device__ __forceinline__ floatx2 h2f2(h2 a) {
  floatx2 r; r.x = (float)a.x; r.y = (float)a.y; return r;
}

// ---------------- casts / transposes ----------------

__global__ void cast_x_kernel(const float* __restrict__ x, unsigned short* __restrict__ xa,
                              int* __restrict__ counts, int* __restrict__ cursor) {
  int idx = blockIdx.x * 256 + threadIdx.x;       // over N_NODES * K1PAD
  if (idx < N_NODES) { counts[idx] = 0; cursor[idx] = 0; }  // replaces 2 memsets
  if (idx >= N_NODES * K1PAD) return;
  int m = idx / K1PAD, k = idx - m * K1PAD;
  float v = (k < IN_CH) ? x[m * IN_CH + k] : 0.f;
  xa[idx] = f2bf(v);
}

// out[n*Kout + k] = (k < Kvalid ? W[k][n] : 0); W col picked from wa/wb by split
__global__ void transpose_cast_kernel(const float* __restrict__ wa, const float* __restrict__ wb,
                                      int split, int lda, int ldb,
                                      int Kvalid, int Kout, unsigned short* __restrict__ out) {
  __shared__ float tile[32][33];
  int n0 = blockIdx.x * 32, k0 = blockIdx.y * 32;
  int tx = threadIdx.x, ty = threadIdx.y;  // 32 x 8
#pragma unroll
  for (int i = 0; i < 4; i++) {
    int k = k0 + ty + i * 8;
    int n = n0 + tx;
    float v = 0.f;
    if (k < Kvalid) v = (n < split) ? wa[(size_t)k * lda + n] : wb[(size_t)k * ldb + (n - split)];
    tile[ty + i * 8][tx] = v;
  }
  __syncthreads();
#pragma unroll
  for (int i = 0; i < 4; i++) {
    int n = n0 + ty + i * 8;
    int k = k0 + tx;
    out[(size_t)n * Kout + k] = f2bf(tile[tx][ty + i * 8]);
  }
}

// ---------------- CSR build (group edges by dst; store SRC ids directly) ----------------

__global__ void count_kernel(const int* __restrict__ dstArr, int* __restrict__ counts) {
  int e = blockIdx.x * 256 + threadIdx.x;
  if (e >= E_TOT) return;
  int d = (e < N_EDGES) ? dstArr[e] : (e - N_EDGES);
  atomicAdd(&counts[d], 1);
}

// two-level exclusive scan, 256 threads, 40 elems/thread serial
__global__ __launch_bounds__(256) void scan_kernel(const int* __restrict__ counts,
                                                   int* __restrict__ rstart) {
  __shared__ int sm[256];
  int t = threadIdx.x;
  int b0 = t * 40;
  int b1 = b0 + 40; if (b1 > N_NODES) b1 = N_NODES; if (b0 > N_NODES) b0 = N_NODES;
  int s = 0;
  for (int i = b0; i < b1; i++) s += counts[i];
  sm[t] = s; __syncthreads();
  for (int st = 1; st < 256; st <<= 1) {
    int add = (t >= st) ? sm[t - st] : 0;
    __syncthreads();
    sm[t] += add;
    __syncthreads();
  }
  int run = sm[t] - s;   // exclusive prefix of this thread's chunk
  for (int i = b0; i < b1; i++) { rstart[i] = run; run += counts[i]; }
  if (t == 255) rstart[N_NODES] = run;
}

__global__ void scatter_kernel(const int* __restrict__ srcArr, const int* __restrict__ dstArr,
                               const int* __restrict__ row_start,
                               int* __restrict__ cursor, int* __restrict__ csrsrc) {
  int e = blockIdx.x * 256 + threadIdx.x;
  if (e >= E_TOT) return;
  int d, sv;
  if (e < N_EDGES) { d = dstArr[e]; sv = srcArr[e]; }
  else { d = e - N_EDGES; sv = d; }     // self loop: src == dst
  int pos = atomicAdd(&cursor[d], 1);
  csrsrc[row_start[d] + pos] = sv;
}

// ---------------- bf16 MFMA GEMM: 128x128 tile, BK=64, XOR-swizzled LDS ----------------
// KC compile-time (staging strides fold to SGPRs); __launch_bounds__(256,4) forces
// 4 waves/SIMD residency. MODE 0: Cf = v+bias; MODE 1: ELU -> Cf;
// MODE 2: all-FP16 -> Cb[m*2048+n] (xlr feeds only gat_ln; f16 > bf16 precision).
template <int MODE, int KC>
__global__ __launch_bounds__(256, 4) void gemm_bf16(
    const unsigned short* __restrict__ A, const unsigned short* __restrict__ Bt,
    float* __restrict__ Cf, unsigned short* __restrict__ Cb,
    const float* __restrict__ blo, const float* __restrict__ bhi,
    int M, int ldc, int bsplit)
{
  __shared__ __align__(16) unsigned short As[128 * 64];
  __shared__ __align__(16) unsigned short Bs[128 * 64];
  const int t = threadIdx.x;
  const int w = t >> 6, lane = t & 63;
  const int tile_n = blockIdx.x * 128, tile_m = blockIdx.y * 128;   // x = N-tile: L2 share

  floatx4 acc[4][4] = {};

  // staging geometry: slot q = p*256 + w*64 + lane; row = q>>3; sj = q&7; gj = sj ^ (row&7)
  const int q = w * 64 + lane;          // 0..255 (p-invariant part)
  const int row0 = q >> 3;              // 0..31; row_p = row0 + p*32 (row&7 p-invariant)
  const int gj = (q & 7) ^ (row0 & 7);
  const unsigned short* gA0 = A  + (size_t)(tile_m + row0) * KC + gj * 8;
  const unsigned short* gB0 = Bt + (size_t)(tile_n + row0) * KC + gj * 8;

  const int wm = (w >> 1) * 64, wn = (w & 1) * 64;
  const int lrow = lane & 15, cg0 = (lane >> 4);
  const int sw = lrow & 7;              // row&7 of every fragment row this lane reads

#pragma unroll 1
  for (int k0 = 0; k0 < KC; k0 += 64) {
#pragma unroll
    for (int p = 0; p < 4; p++) {
      __builtin_amdgcn_global_load_lds(
          (const __attribute__((address_space(1))) void*)(gA0 + p * 32 * KC),
          (__attribute__((address_space(3))) void*)(As + p * 2048 + w * 512), 16, 0, 0);
      __builtin_amdgcn_global_load_lds(
          (const __attribute__((address_space(1))) void*)(gB0 + p * 32 * KC),
          (__attribute__((address_space(3))) void*)(Bs + p * 2048 + w * 512), 16, 0, 0);
    }
    gA0 += 64; gB0 += 64;
    __syncthreads();
#pragma unroll
    for (int h = 0; h < 2; h++) {
      const int sc = (h * 4 + cg0) ^ sw;   // swizzled chunk slot
      bf16x8 a[4], b[4];
#pragma unroll
      for (int mi = 0; mi < 4; mi++)
        a[mi] = *(const bf16x8*)(As + (wm + mi * 16 + lrow) * 64 + sc * 8);
#pragma unroll
      for (int ni = 0; ni < 4; ni++)
        b[ni] = *(const bf16x8*)(Bs + (wn + ni * 16 + lrow) * 64 + sc * 8);
#pragma unroll
      for (int mi = 0; mi < 4; mi++)
#pragma unroll
        for (int ni = 0; ni < 4; ni++)
          acc[mi][ni] = __builtin_amdgcn_mfma_f32_16x16x32_bf16(a[mi], b[ni], acc[mi][ni], 0, 0, 0);
    }
    __syncthreads();
  }

  const int rbase = (lane >> 4) * 4;
#pragma unroll
  for (int mi = 0; mi < 4; mi++) {
#pragma unroll
    for (int r = 0; r < 4; r++) {
      int m = tile_m + wm + mi * 16 + rbase + r;
      if (m >= M) continue;
#pragma unroll
      for (int ni = 0; ni < 4; ni++) {
        int n = tile_n + wn + ni * 16 + lrow;
        float v = acc[mi][ni][r] + (n < bsplit ? blo[n] : bhi[n - bsplit]);
        if (MODE == 0) {
          Cf[(size_t)m * ldc + n] = v;
        } else if (MODE == 1) {
          Cf[(size_t)m * ldc + n] = v > 0.f ? v : expm1f(v);
        } else {  // all-f16: xl = cols 0..1023, xr = cols 1024..2047
          Cb[(size_t)m * 2048 + n] = f2h(v);
        }
      }
    }
  }
}

// ---------------- fused GATv2 edge phase + LayerNorm + ELU -> bf16 -------------
// R9 structure (4 ch/lane, full-wave 6-step reduce, wave==head, 4-edge unroll).
// xlr stored FP16; score path = packed-f16 (v_pk_add/mul/max_f16) + v_dot2_f32_f16
// (1 inst per 2 ch, f32 accum). att pre-scaled by log2e -> softmax exps are bare
// v_exp_f32 (exp2f). Aggregation stays fp32.

__global__ __launch_bounds__(256) void gat_ln_kernel(
    const unsigned short* __restrict__ xlr,  // [N,2048] f16: xl cols 0..1023, xr 1024..2047
    const float* __restrict__ att,           // [4,256] fp32
    const int* __restrict__ csrsrc, const int* __restrict__ rstart,
    const float* __restrict__ bias,
    const float* __restrict__ lnw, const float* __restrict__ lnb,
    unsigned short* __restrict__ out)        // [N,1024] bf16
{
  const int d = blockIdx.x;
  const int t = threadIdx.x;
  const int lane = t & 63, wv = t >> 6;
  const int c = wv * 256 + lane * 4;   // 4 channels of head wv

  uint2 xru = *(const uint2*)(xlr + (size_t)d * 2048 + 1024 + c);
  h2 xr0 = bits2h2(xru.x), xr1 = bits2h2(xru.y);
  float4 aw4 = *(const float4*)(att + c);
  h2 aw0, aw1;   // att * log2e in f16 (scores move to log2 domain)
  aw0.x = (_Float16)(aw4.x * LOG2E); aw0.y = (_Float16)(aw4.y * LOG2E);
  aw1.x = (_Float16)(aw4.z * LOG2E); aw1.y = (_Float16)(aw4.w * LOG2E);
  const h2 ns = {(_Float16)NEG_SLOPE, (_Float16)NEG_SLOPE};
  const unsigned short* xbase = xlr + c;

  int start = rstart[d], deg = rstart[d + 1] - start;

  float m = -3.0e38f, l = 0.f;
  floatx2 accA = {0.f, 0.f}, accB = {0.f, 0.f};

  int i = 0;
  for (; i + 4 <= deg; i += 4) {
    int s0 = csrsrc[start + i],     s1 = csrsrc[start + i + 1];
    int s2 = csrsrc[start + i + 2], s3 = csrsrc[start + i + 3];
    uint2 u0 = *(const uint2*)(xbase + (size_t)s0 * 2048);
    uint2 u1 = *(const uint2*)(xbase + (size_t)s1 * 2048);
    uint2 u2 = *(const uint2*)(xbase + (size_t)s2 * 2048);
    uint2 u3 = *(const uint2*)(xbase + (size_t)s3 * 2048);
    h2 xh0a = bits2h2(u0.x), xh0b = bits2h2(u0.y);
    h2 xh1a = bits2h2(u1.x), xh1b = bits2h2(u1.y);
    h2 xh2a = bits2h2(u2.x), xh2b = bits2h2(u2.y);
    h2 xh3a = bits2h2(u3.x), xh3b = bits2h2(u3.y);
    h2 t0a = xh0a + xr0, t0b = xh0b + xr1;
    h2 t1a = xh1a + xr0, t1b = xh1b + xr1;
    h2 t2a = xh2a + xr0, t2b = xh2b + xr1;
    h2 t3a = xh3a + xr0, t3b = xh3b + xr1;
    h2 r0a = __builtin_elementwise_max(t0a, t0a * ns);
    h2 r0b = __builtin_elementwise_max(t0b, t0b * ns);
    h2 r1a = __builtin_elementwise_max(t1a, t1a * ns);
    h2 r1b = __builtin_elementwise_max(t1b, t1b * ns);
    h2 r2a = __builtin_elementwise_max(t2a, t2a * ns);
    h2 r2b = __builtin_elementwise_max(t2b, t2b * ns);
    h2 r3a = __builtin_elementwise_max(t3a, t3a * ns);
    h2 r3b = __builtin_elementwise_max(t3b, t3b * ns);
    float p0 = __builtin_amdgcn_fdot2(r0b, aw1, __builtin_amdgcn_fdot2(r0a, aw0, 0.f, false), false);
    float p1 = __builtin_amdgcn_fdot2(r1b, aw1, __builtin_amdgcn_fdot2(r1a, aw0, 0.f, false), false);
    float p2 = __builtin_amdgcn_fdot2(r2b, aw1, __builtin_amdgcn_fdot2(r2a, aw0, 0.f, false), false);
    float p3 = __builtin_amdgcn_fdot2(r3b, aw1, __builtin_amdgcn_fdot2(r3a, aw0, 0.f, false), false);
#pragma unroll
    for (int mm = 32; mm >= 1; mm >>= 1) {
      p0 += __shfl_xor(p0, mm, 64);
      p1 += __shfl_xor(p1, mm, 64);
      p2 += __shfl_xor(p2, mm, 64);
      p3 += __shfl_xor(p3, mm, 64);
    }
    float mx = fmaxf(fmaxf(p0, p1), fmaxf(p2, p3));
    if (mx > m) {                        // wave-uniform branch (p,m uniform after reduce)
      float sc = exp2f(m - mx);
      floatx2 scv; scv.x = sc; scv.y = sc;
      accA *= scv; accB *= scv; l *= sc;
      m = mx;
    }
    float pe0 = exp2f(p0 - m), pe1 = exp2f(p1 - m);
    float pe2 = exp2f(p2 - m), pe3 = exp2f(p3 - m);
    floatx2 x0A = h2f2(xh0a), x0B = h2f2(xh0b);
    floatx2 x1A = h2f2(xh1a), x1B = h2f2(xh1b);
    floatx2 x2A = h2f2(xh2a), x2B = h2f2(xh2b);
    floatx2 x3A = h2f2(xh3a), x3B = h2f2(xh3b);
    floatx2 v0; v0.x = pe0; v0.y = pe0;
    floatx2 v1; v1.x = pe1; v1.y = pe1;
    floatx2 v2; v2.x = pe2; v2.y = pe2;
    floatx2 v3; v3.x = pe3; v3.y = pe3;
    accA += x0A * v0; accA += x1A * v1; accA += x2A * v2; accA += x3A * v3;
    accB += x0B * v0; accB += x1B * v1; accB += x2B * v2; accB += x3B * v3;
    l += pe0 + pe1 + pe2 + pe3;
  }
  for (; i < deg; i++) {
    int s0 = csrsrc[start + i];
    uint2 u0 = *(const uint2*)(xbase + (size_t)s0 * 2048);
    h2 xh0a = bits2h2(u0.x), xh0b = bits2h2(u0.y);
    h2 t0a = xh0a + xr0, t0b = xh0b + xr1;
    h2 r0a = __builtin_elementwise_max(t0a, t0a * ns);
    h2 r0b = __builtin_elementwise_max(t0b, t0b * ns);
    float p0 = __builtin_amdgcn_fdot2(r0b, aw1, __builtin_amdgcn_fdot2(r0a, aw0, 0.f, false), false);
#pragma unroll
    for (int mm = 32; mm >= 1; mm >>= 1) p0 += __shfl_xor(p0, mm, 64);
    if (p0 > m) {
      float sc = exp2f(m - p0);
      floatx2 scv; scv.x = sc; scv.y = sc;
      accA *= scv; accB *= scv; l *= sc;
      m = p0;
    }
    float pe0 = exp2f(p0 - m);
    floatx2 x0A = h2f2(xh0a), x0B = h2f2(xh0b);
    floatx2 pe0v; pe0v.x = pe0; pe0v.y = pe0;
    accA += x0A * pe0v;
    accB += x0B * pe0v;
    l += pe0;
  }

  float rd = 1.f / (l + 1e-16f);
  float4 bv = *(const float4*)(bias + c);
  float o0 = accA.x * rd + bv.x, o1 = accA.y * rd + bv.y;
  float o2 = accB.x * rd + bv.z, o3 = accB.y * rd + bv.w;

  // LayerNorm over the 1024 channels held by this block
  __shared__ float ws1[4], ws2[4];
  float s1 = o0 + o1 + o2 + o3;
  float s2 = o0 * o0 + o1 * o1 + o2 * o2 + o3 * o3;
#pragma unroll
  for (int mm = 32; mm >= 1; mm >>= 1) {
    s1 += __shfl_xor(s1, mm, 64);
    s2 += __shfl_xor(s2, mm, 64);
  }
  if (lane == 0) { ws1[wv] = s1; ws2[wv] = s2; }
  __syncthreads();
  float mean = (ws1[0] + ws1[1] + ws1[2] + ws1[3]) * (1.f / 1024.f);
  float var  = (ws2[0] + ws2[1] + ws2[2] + ws2[3]) * (1.f / 1024.f) - mean * mean;
  float rstd = rsqrtf(var + LN_EPS);
  float4 wv4 = *(const float4*)(lnw + c);
  float4 bb  = *(const float4*)(lnb + c);
  float z0 = (o0 - mean) * rstd * wv4.x + bb.x; z0 = z0 > 0.f ? z0 : expm1f(z0);
  float z1 = (o1 - mean) * rstd * wv4.y + bb.y; z1 = z1 > 0.f ? z1 : expm1f(z1);
  float z2 = (o2 - mean) * rstd * wv4.z + bb.z; z2 = z2 > 0.f ? z2 : expm1f(z2);
  float z3 = (o3 - mean) * rstd * wv4.w + bb.w; z3 = z3 > 0.f ? z3 : expm1f(z3);
  ushort4 u;
  u.x = f2bf(z0); u.y = f2bf(z1); u.z = f2bf(z2); u.w = f2bf(z3);
  *(ushort4*)(out + (size_t)d * 1024 + c) = u;
}

// ---------------- final tiny GEMM: out[node][49] = h3 . w2 + b2 ----------------
// 10000 blocks x 64 threads; w2 in native k-major layout -> coalesced (R11 win).

__global__ __launch_bounds__(64) void cls2_kernel(
    const float* __restrict__ h3, const float* __restrict__ w2,
    const float* __restrict__ b2, float* __restrict__ out)
{
  __shared__ float row[256];
  int node = blockIdx.x, t = threadIdx.x;
  *(float4*)(row + t * 4) = *(const float4*)(h3 + (size_t)node * 256 + t * 4);
  __syncthreads();
  if (t < OUT_CH) {
    float a0 = 0.f, a1 = 0.f, a2 = 0.f, a3 = 0.f;
#pragma unroll 4
    for (int k = 0; k < 256; k += 4) {
      float4 r = *(const float4*)(row + k);       // uniform addr -> LDS broadcast
      a0 += r.x * w2[(k + 0) * OUT_CH + t];       // lanes consecutive -> coalesced
      a1 += r.y * w2[(k + 1) * OUT_CH + t];
      a2 += r.z * w2[(k + 2) * OUT_CH + t];
      a3 += r.w * w2[(k + 3) * OUT_CH + t];
    }
    out[node * OUT_CH + t] = (a0 + a1) + (a2 + a3) + b2[t];
  }
}

// ---------------- launch ----------------

extern "C" void kernel_launch(void* const* d_in, const int* in_sizes, int n_in,
                              void* d_out, int out_size, void* d_ws, size_t ws_size,
                              hipStream_t stream)
{
  const float* x       = (const float*)d_in[0];
  const int*   ei      = (const int*)d_in[1];
  const float* c1_wl   = (const float*)d_in[2];
  const float* c1_bl   = (const float*)d_in[3];
  const float* c1_wr   = (const float*)d_in[4];
  const float* c1_br   = (const float*)d_in[5];
  const float* c1_att  = (const float*)d_in[6];
  const float* c1_bias = (const float*)d_in[7];
  const float* ln1_w   = (const float*)d_in[8];
  const float* ln1_b   = (const float*)d_in[9];
  const float* c2_wl   = (const float*)d_in[10];
  const float* c2_bl   = (const float*)d_in[11];
  const float* c2_wr   = (const float*)d_in[12];
  const float* c2_br   = (const float*)d_in[13];
  const float* c2_att  = (const float*)d_in[14];
  const float* c2_bias = (const float*)d_in[15];
  const float* ln2_w   = (const float*)d_in[16];
  const float* ln2_b   = (const float*)d_in[17];
  const float* cls_w1  = (const float*)d_in[18];
  const float* cls_b1  = (const float*)d_in[19];
  const float* cls_w2  = (const float*)d_in[20];
  const float* cls_b2  = (const float*)d_in[21];

  const int* srcArr = ei;
  const int* dstArr = ei + N_EDGES;

  char* ws = (char*)d_ws;
  size_t off = 0;
  auto alloc = [&](size_t bytes) { void* p = ws + off; off += (bytes + 255) & ~(size_t)255; return p; };
  unsigned short* xa      = (unsigned short*)alloc((size_t)MPAD * K1PAD * 2);
  unsigned short* wt1     = (unsigned short*)alloc((size_t)2048 * K1PAD * 2);
  unsigned short* wt2     = (unsigned short*)alloc((size_t)2048 * 1024 * 2);
  unsigned short* wtc1    = (unsigned short*)alloc((size_t)256 * 1024 * 2);
  unsigned short* xlr     = (unsigned short*)alloc((size_t)N_NODES * 2048 * 2);  // f16 xl|xr
  float*          h3      = (float*)alloc((size_t)N_NODES * 256 * 4);
  unsigned short* hb      = (unsigned short*)alloc((size_t)MPAD * 1024 * 2);
  int*            counts  = (int*)alloc(N_NODES * 4);
  int*            cursor  = (int*)alloc(N_NODES * 4);
  int*            rstart  = (int*)alloc((N_NODES + 1) * 4);
  int*            csrsrc  = (int*)alloc(E_TOT * 4);
  (void)in_sizes; (void)n_in; (void)out_size; (void)ws_size;

  // prep (cast_x also zeroes counts/cursor — replaces 2 memsets)
  cast_x_kernel<<<(N_NODES * K1PAD + 255) / 256, 256, 0, stream>>>(x, xa, counts, cursor);
  transpose_cast_kernel<<<dim3(64, 34), dim3(32, 8), 0, stream>>>(c1_wl, c1_wr, 1024, 1024, 1024, IN_CH, K1PAD, wt1);
  transpose_cast_kernel<<<dim3(64, 32), dim3(32, 8), 0, stream>>>(c2_wl, c2_wr, 1024, 1024, 1024, 1024, 1024, wt2);
  transpose_cast_kernel<<<dim3(8, 32), dim3(32, 8), 0, stream>>>(cls_w1, cls_w1, 256, 256, 256, 1024, 1024, wtc1);

  // CSR by dst (payload = src node id)
  count_kernel<<<(E_TOT + 255) / 256, 256, 0, stream>>>(dstArr, counts);
  scan_kernel<<<1, 256, 0, stream>>>(counts, rstart);
  scatter_kernel<<<(E_TOT + 255) / 256, 256, 0, stream>>>(srcArr, dstArr, rstart, cursor, csrsrc);

  // layer 1
  gemm_bf16<2, K1PAD><<<dim3(16, 79), 256, 0, stream>>>(xa, wt1, nullptr, xlr, c1_bl, c1_br, N_NODES, 0, 1024);
  gat_ln_kernel<<<N_NODES, 256, 0, stream>>>(xlr, c1_att, csrsrc, rstart, c1_bias, ln1_w, ln1_b, hb);

  // layer 2
  gemm_bf16<2, 1024><<<dim3(16, 79), 256, 0, stream>>>(hb, wt2, nullptr, xlr, c2_bl, c2_br, N_NODES, 0, 1024);
  gat_ln_kernel<<<N_NODES, 256, 0, stream>>>(xlr, c2_att, csrsrc, rstart, c2_bias, ln2_w, ln2_b, hb);

  // classifier
  gemm_bf16<1, 1024><<<dim3(2, 79), 256, 0, stream>>>(hb, wtc1, h3, nullptr, cls_b1, cls_b1, N_NODES, 256, 1024);
  cls2_kernel<<<N_NODES, 64, 0, stream>>>(h3, cls_w2, cls_b2, (float*)d_out);
}